// Round 6
// baseline (888.886 us; speedup 1.0000x reference)
//
#include <hip/hip_runtime.h>

#define NN 100000
#define NE 1600000
#define NB 391          // ceil(NN/256) blocks for scan
#define BN_EPS 1e-5f

// ---------------- degree count (int) ----------------
__global__ void k_zero_int(int* __restrict__ p, int n) {
    int i = blockIdx.x * 256 + threadIdx.x;
    if (i < n) p[i] = 0;
}

__global__ void k_count_deg(const int* __restrict__ dst, int* __restrict__ deg) {
    int e = blockIdx.x * 256 + threadIdx.x;
    if (e < NE) atomicAdd(&deg[dst[e]], 1);
}

__global__ void k_dinv(const int* __restrict__ deg, float* __restrict__ dinv) {
    int i = blockIdx.x * 256 + threadIdx.x;
    if (i < NN) dinv[i] = rsqrtf((float)deg[i] + 1.0f);
}

// ---------------- hierarchical exclusive scan of deg -> offsets (in place) ----------------
__global__ __launch_bounds__(256) void k_scan_blocksums(const int* __restrict__ deg,
                                                        int* __restrict__ blk) {
    __shared__ int s[256];
    int i = blockIdx.x * 256 + threadIdx.x;
    s[threadIdx.x] = (i < NN) ? deg[i] : 0;
    __syncthreads();
    for (int off = 128; off > 0; off >>= 1) {
        if (threadIdx.x < off) s[threadIdx.x] += s[threadIdx.x + off];
        __syncthreads();
    }
    if (threadIdx.x == 0) blk[blockIdx.x] = s[0];
}

__global__ __launch_bounds__(512) void k_scan_toplevel(int* __restrict__ blk) {
    __shared__ int s[512];
    int t = threadIdx.x;
    int v = (t < NB) ? blk[t] : 0;
    s[t] = v;
    for (int off = 1; off < 512; off <<= 1) {
        __syncthreads();
        int x = (t >= off) ? s[t - off] : 0;
        __syncthreads();
        s[t] += x;
    }
    __syncthreads();
    if (t < NB) blk[t] = s[t] - v;   // exclusive
}

__global__ __launch_bounds__(256) void k_scan_final(int* __restrict__ degoff,
                                                    const int* __restrict__ blk) {
    __shared__ int s[256];
    int t = threadIdx.x;
    int i = blockIdx.x * 256 + t;
    int v = (i < NN) ? degoff[i] : 0;
    s[t] = v;
    for (int off = 1; off < 256; off <<= 1) {
        __syncthreads();
        int x = (t >= off) ? s[t - off] : 0;
        __syncthreads();
        s[t] += x;
    }
    __syncthreads();
    if (i < NN) degoff[i] = s[t] - v + blk[blockIdx.x];  // exclusive + block prefix
    if (i == 0) degoff[NN] = NE;
}

// ---------------- CSR fill ----------------
__global__ void k_csr_fill(const int* __restrict__ src, const int* __restrict__ dst,
                           const int* __restrict__ off, int* __restrict__ cur,
                           int* __restrict__ csr) {
    int e = blockIdx.x * 256 + threadIdx.x;
    if (e >= NE) return;
    int n = dst[e];
    int p = atomicAdd(&cur[n], 1);
    csr[off[n] + p] = src[e];
}

#define FMA4(ACC, AV)                                                     \
    ACC.x += AV.x * w0.x + AV.y * w1.x + AV.z * w2.x + AV.w * w3.x;       \
    ACC.y += AV.x * w0.y + AV.y * w1.y + AV.z * w2.y + AV.w * w3.y;       \
    ACC.z += AV.x * w0.z + AV.y * w1.z + AV.z * w2.z + AV.w * w3.z;       \
    ACC.w += AV.x * w0.w + AV.y * w1.w + AV.z * w2.w + AV.w * w3.w;

// ================ fused layer 1: gather(x*dinv) + GEMM(64->128) + BN + ReLU + *dinv ================
// Block = 32 nodes (NN % 32 == 0). Gather phase fills sAgg[32][64]; W1 staged
// under it; then 4x4 register-tile GEMM from pure LDS; BN/ReLU/dinv epilogue.
__global__ __launch_bounds__(256) void k_fused1(
        const float* __restrict__ x, const int* __restrict__ off,
        const int* __restrict__ csr, const float* __restrict__ dinv,
        const float* __restrict__ W1, const float* __restrict__ b1,
        const float* __restrict__ g1, const float* __restrict__ be1,
        const float* __restrict__ m1, const float* __restrict__ v1,
        float* __restrict__ h1ps) {
    __shared__ float sAgg[32 * 64];      // 8 KB
    __shared__ float sW[64 * 128];       // 32 KB
    int tid  = threadIdx.x;
    int n0   = blockIdx.x * 32;
    int wave = tid >> 6, lane = tid & 63;

    // stage W1 fully (issued first; gather hides the latency)
    {
        const float4* s = (const float4*)W1;
        float4* d = (float4*)sW;
#pragma unroll
        for (int i = 0; i < 8; ++i) d[tid + 256 * i] = s[tid + 256 * i];
    }

    // gather: wave handles 8 nodes, lane owns one column
    for (int i = 0; i < 8; ++i) {
        int n = n0 + wave * 8 + i;
        int beg = off[n], end = off[n + 1];
        float a0 = 0.f, a1 = 0.f, a2 = 0.f, a3 = 0.f;
        int e = beg;
        for (; e + 4 <= end; e += 4) {
            int s0 = csr[e], s1 = csr[e + 1], s2 = csr[e + 2], s3 = csr[e + 3];
            a0 += x[(size_t)s0 * 64 + lane] * dinv[s0];
            a1 += x[(size_t)s1 * 64 + lane] * dinv[s1];
            a2 += x[(size_t)s2 * 64 + lane] * dinv[s2];
            a3 += x[(size_t)s3 * 64 + lane] * dinv[s3];
        }
        for (; e < end; ++e) {
            int s0 = csr[e];
            a0 += x[(size_t)s0 * 64 + lane] * dinv[s0];
        }
        float dn = dinv[n];
        sAgg[(wave * 8 + i) * 64 + lane] =
            (a0 + a1 + a2 + a3 + x[(size_t)n * 64 + lane] * dn) * dn;
    }
    __syncthreads();

    // GEMM: 32 rows x 128 cols, thread = 4 rows x 4 cols (cg 0..31, rg 0..7)
    int cg = tid & 31, rg = tid >> 5;
    const float4* a4 = (const float4*)sAgg;   // row stride 16 float4
    const float4* w4 = (const float4*)sW;     // row stride 32 float4
    float4 acc[4];
#pragma unroll
    for (int j = 0; j < 4; ++j) acc[j] = make_float4(0.f, 0.f, 0.f, 0.f);

#pragma unroll
    for (int kk = 0; kk < 16; ++kk) {
        float4 A0 = a4[(rg * 4 + 0) * 16 + kk];
        float4 A1 = a4[(rg * 4 + 1) * 16 + kk];
        float4 A2 = a4[(rg * 4 + 2) * 16 + kk];
        float4 A3 = a4[(rg * 4 + 3) * 16 + kk];
        float4 w0 = w4[(kk * 4 + 0) * 32 + cg];
        float4 w1 = w4[(kk * 4 + 1) * 32 + cg];
        float4 w2 = w4[(kk * 4 + 2) * 32 + cg];
        float4 w3 = w4[(kk * 4 + 3) * 32 + cg];
        FMA4(acc[0], A0)
        FMA4(acc[1], A1)
        FMA4(acc[2], A2)
        FMA4(acc[3], A3)
    }

    // BN consts per column: val = acc*sc + sh
    float sc[4], sh[4];
#pragma unroll
    for (int j = 0; j < 4; ++j) {
        int c = cg * 4 + j;
        float s = g1[c] * rsqrtf(v1[c] + BN_EPS);
        sc[j] = s;
        sh[j] = (b1[c] - m1[c]) * s + be1[c];
    }
#pragma unroll
    for (int j = 0; j < 4; ++j) {
        int r = n0 + rg * 4 + j;
        float d = dinv[r];
        float4 o = acc[j];
        o.x = fmaxf(o.x * sc[0] + sh[0], 0.f) * d;
        o.y = fmaxf(o.y * sc[1] + sh[1], 0.f) * d;
        o.z = fmaxf(o.z * sc[2] + sh[2], 0.f) * d;
        o.w = fmaxf(o.w * sc[3] + sh[3], 0.f) * d;
        ((float4*)h1ps)[(size_t)r * 32 + cg] = o;
    }
}

// ================ fused layers 2+3: gather(h1ps) + GEMM(128->128) + BN + ReLU
//                  + GEMM(128->64) + *dinv ================
// sAgg[32][128] holds the aggregate, then is overwritten with h2p for GEMM3.
// sW (16 KB) holds W2 in 4 chunks of 32 k-rows, then W3 in 2 chunks of 64.
__global__ __launch_bounds__(256) void k_fused23(
        const float* __restrict__ h1ps, const int* __restrict__ off,
        const int* __restrict__ csr, const float* __restrict__ dinv,
        const float* __restrict__ W2, const float* __restrict__ b2,
        const float* __restrict__ g2, const float* __restrict__ be2,
        const float* __restrict__ m2, const float* __restrict__ v2,
        const float* __restrict__ W3, float* __restrict__ hs3) {
    __shared__ float sAgg[32 * 128];     // 16 KB
    __shared__ float sW[32 * 128];       // 16 KB (also fits W3 chunk 64x64)
    int tid  = threadIdx.x;
    int n0   = blockIdx.x * 32;
    int wave = tid >> 6, lane = tid & 63;

    // stage W2 chunk 0 (hidden under gather)
    {
        const float4* s = (const float4*)W2;
        float4* d = (float4*)sW;
#pragma unroll
        for (int i = 0; i < 4; ++i) d[tid + 256 * i] = s[tid + 256 * i];
    }

    // gather: wave per node, lane owns 2 columns (float2)
    const float2* h2 = (const float2*)h1ps;
    float2* sAgg2 = (float2*)sAgg;
    for (int i = 0; i < 8; ++i) {
        int n = n0 + wave * 8 + i;
        int beg = off[n], end = off[n + 1];
        float ax = 0.f, ay = 0.f, bx = 0.f, by = 0.f;
        int e = beg;
        for (; e + 4 <= end; e += 4) {
            int s0 = csr[e], s1 = csr[e + 1], s2 = csr[e + 2], s3 = csr[e + 3];
            float2 u0 = h2[(size_t)s0 * 64 + lane];
            float2 u1 = h2[(size_t)s1 * 64 + lane];
            float2 u2 = h2[(size_t)s2 * 64 + lane];
            float2 u3 = h2[(size_t)s3 * 64 + lane];
            ax += u0.x; ay += u0.y;
            bx += u1.x; by += u1.y;
            ax += u2.x; ay += u2.y;
            bx += u3.x; by += u3.y;
        }
        for (; e < end; ++e) {
            float2 u0 = h2[(size_t)csr[e] * 64 + lane];
            ax += u0.x; ay += u0.y;
        }
        float dn = dinv[n];
        float2 self = h2[(size_t)n * 64 + lane];
        float2 o;
        o.x = (ax + bx + self.x) * dn;
        o.y = (ay + by + self.y) * dn;
        sAgg2[(wave * 8 + i) * 64 + lane] = o;
    }

    // ---- GEMM2: 32x128 @ 128x128, K chunked by 32 ----
    int cg = tid & 31, rg = tid >> 5;
    const float4* a4 = (const float4*)sAgg;   // row stride 32 float4
    const float4* w4 = (const float4*)sW;
    float4 acc[4];
#pragma unroll
    for (int j = 0; j < 4; ++j) acc[j] = make_float4(0.f, 0.f, 0.f, 0.f);

    for (int ch = 0; ch < 4; ++ch) {
        if (ch > 0) {
            __syncthreads();   // all waves done reading previous sW chunk
            const float4* s = (const float4*)(W2 + (size_t)ch * 32 * 128);
            float4* d = (float4*)sW;
#pragma unroll
            for (int i = 0; i < 4; ++i) d[tid + 256 * i] = s[tid + 256 * i];
        }
        __syncthreads();       // sW chunk ready (and on ch=0: sAgg ready)
#pragma unroll
        for (int kk = 0; kk < 8; ++kk) {
            float4 A0 = a4[(rg * 4 + 0) * 32 + ch * 8 + kk];
            float4 A1 = a4[(rg * 4 + 1) * 32 + ch * 8 + kk];
            float4 A2 = a4[(rg * 4 + 2) * 32 + ch * 8 + kk];
            float4 A3 = a4[(rg * 4 + 3) * 32 + ch * 8 + kk];
            float4 w0 = w4[(kk * 4 + 0) * 32 + cg];
            float4 w1 = w4[(kk * 4 + 1) * 32 + cg];
            float4 w2 = w4[(kk * 4 + 2) * 32 + cg];
            float4 w3 = w4[(kk * 4 + 3) * 32 + cg];
            FMA4(acc[0], A0)
            FMA4(acc[1], A1)
            FMA4(acc[2], A2)
            FMA4(acc[3], A3)
        }
    }

    // BN + ReLU into registers (h2p tile)
    float sc[4], sh[4];
#pragma unroll
    for (int j = 0; j < 4; ++j) {
        int c = cg * 4 + j;
        float s = g2[c] * rsqrtf(v2[c] + BN_EPS);
        sc[j] = s;
        sh[j] = (b2[c] - m2[c]) * s + be2[c];
    }
    float4 hp[4];
#pragma unroll
    for (int j = 0; j < 4; ++j) {
        float4 o = acc[j];
        o.x = fmaxf(o.x * sc[0] + sh[0], 0.f);
        o.y = fmaxf(o.y * sc[1] + sh[1], 0.f);
        o.z = fmaxf(o.z * sc[2] + sh[2], 0.f);
        o.w = fmaxf(o.w * sc[3] + sh[3], 0.f);
        hp[j] = o;
    }

    __syncthreads();   // everyone done reading sAgg and sW (GEMM2 complete)
    // overwrite sAgg with h2p; stage W3 chunk 0 (64x64)
#pragma unroll
    for (int j = 0; j < 4; ++j)
        ((float4*)sAgg)[(rg * 4 + j) * 32 + cg] = hp[j];
    {
        const float4* s = (const float4*)W3;
        float4* d = (float4*)sW;
#pragma unroll
        for (int i = 0; i < 4; ++i) d[tid + 256 * i] = s[tid + 256 * i];
    }
    __syncthreads();   // h2p + W3 chunk 0 ready

    // ---- GEMM3: 32x64 @ 128x64, K chunked by 64; thread = 2 rows x 4 cols ----
    int cg3 = tid & 15, rg3 = tid >> 4;       // cols cg3*4.., rows rg3*2..+1
    const float4* w34 = (const float4*)sW;    // row stride 16 float4
    float4 acc3[2];
    acc3[0] = make_float4(0.f, 0.f, 0.f, 0.f);
    acc3[1] = make_float4(0.f, 0.f, 0.f, 0.f);

    for (int ch = 0; ch < 2; ++ch) {
        if (ch == 1) {
            __syncthreads();
            const float4* s = (const float4*)(W3 + 64 * 64);
            float4* d = (float4*)sW;
#pragma unroll
            for (int i = 0; i < 4; ++i) d[tid + 256 * i] = s[tid + 256 * i];
            __syncthreads();
        }
#pragma unroll
        for (int kk = 0; kk < 16; ++kk) {
            float4 A0 = a4[(rg3 * 2 + 0) * 32 + ch * 16 + kk];
            float4 A1 = a4[(rg3 * 2 + 1) * 32 + ch * 16 + kk];
            float4 w0 = w34[(kk * 4 + 0) * 16 + cg3];
            float4 w1 = w34[(kk * 4 + 1) * 16 + cg3];
            float4 w2 = w34[(kk * 4 + 2) * 16 + cg3];
            float4 w3 = w34[(kk * 4 + 3) * 16 + cg3];
            FMA4(acc3[0], A0)
            FMA4(acc3[1], A1)
        }
    }

#pragma unroll
    for (int j = 0; j < 2; ++j) {
        int r = n0 + rg3 * 2 + j;
        float d = dinv[r];
        float4 o = acc3[j];
        o.x *= d; o.y *= d; o.z *= d; o.w *= d;
        ((float4*)hs3)[(size_t)r * 16 + cg3] = o;
    }
}

// ---------------- fused gather + self + bias + ReLU + (·Wo + bo) (M=64) ----------------
__global__ __launch_bounds__(256) void k_gather_final64(
        const float* __restrict__ hs, const int* __restrict__ off,
        const int* __restrict__ csr, const float* __restrict__ dinv,
        const float* __restrict__ b, const float* __restrict__ Wo,
        const float* __restrict__ bo, float* __restrict__ out) {
    int n = blockIdx.x * 4 + (threadIdx.x >> 6);
    if (n >= NN) return;
    int lane = threadIdx.x & 63;

    int beg = off[n], end = off[n + 1];
    float a0 = 0.f, a1 = 0.f, a2 = 0.f, a3 = 0.f;
    int e = beg;
    for (; e + 4 <= end; e += 4) {
        int s0 = csr[e], s1 = csr[e + 1], s2 = csr[e + 2], s3 = csr[e + 3];
        a0 += hs[(size_t)s0 * 64 + lane];
        a1 += hs[(size_t)s1 * 64 + lane];
        a2 += hs[(size_t)s2 * 64 + lane];
        a3 += hs[(size_t)s3 * 64 + lane];
    }
    for (; e < end; ++e) a0 += hs[(size_t)csr[e] * 64 + lane];

    float val = (a0 + a1 + a2 + a3 + hs[(size_t)n * 64 + lane]) * dinv[n] + b[lane];
    val = fmaxf(val, 0.f) * Wo[lane];
#pragma unroll
    for (int o = 32; o > 0; o >>= 1) val += __shfl_down(val, o, 64);
    if (lane == 0) out[n] = val + bo[0];
}

extern "C" void kernel_launch(void* const* d_in, const int* in_sizes, int n_in,
                              void* d_out, int out_size, void* d_ws, size_t ws_size,
                              hipStream_t stream) {
    const float* x   = (const float*)d_in[0];
    const int*   ei  = (const int*)d_in[1];
    const int*   src = ei;
    const int*   dst = ei + NE;
    const float* W1  = (const float*)d_in[2];
    const float* b1  = (const float*)d_in[3];
    const float* g1  = (const float*)d_in[4];
    const float* be1 = (const float*)d_in[5];
    const float* m1  = (const float*)d_in[6];
    const float* v1  = (const float*)d_in[7];
    const float* W2  = (const float*)d_in[8];
    const float* b2  = (const float*)d_in[9];
    const float* g2  = (const float*)d_in[10];
    const float* be2 = (const float*)d_in[11];
    const float* m2  = (const float*)d_in[12];
    const float* v2  = (const float*)d_in[13];
    const float* W3  = (const float*)d_in[14];
    const float* b3  = (const float*)d_in[15];
    const float* Wo  = (const float*)d_in[16];
    const float* bo  = (const float*)d_in[17];
    float* out = (float*)d_out;

    char* ws = (char*)d_ws;
    float* dinv   = (float*)(ws + 0);            // 400,000 B
    int*   degoff = (int*)(ws + 400000);         // (N+1) ints, scanned in place
    int*   cur    = (int*)(ws + 800032);         // 400,000 B
    int*   blk    = (int*)(ws + 1200032);        // NB ints
    int*   csr    = (int*)(ws + 1201600);        // 6,400,000 B
    float* h1ps   = (float*)(ws + 7601600);      // N*128 floats, 51.2 MB
    float* hs3    = (float*)(ws + 58801600);     // N*64 floats, 25.6 MB

    int gN = (NN + 255) / 256;
    int gE = (NE + 255) / 256;
    int gW = (NN + 3) / 4;

    // ---- CSR build + dinv ----
    k_zero_int<<<gN, 256, 0, stream>>>(degoff, NN);
    k_zero_int<<<gN, 256, 0, stream>>>(cur, NN);
    k_count_deg<<<gE, 256, 0, stream>>>(dst, degoff);
    k_dinv<<<gN, 256, 0, stream>>>(degoff, dinv);
    k_scan_blocksums<<<NB, 256, 0, stream>>>(degoff, blk);
    k_scan_toplevel<<<1, 512, 0, stream>>>(blk);
    k_scan_final<<<NB, 256, 0, stream>>>(degoff, blk);
    k_csr_fill<<<gE, 256, 0, stream>>>(src, dst, degoff, cur, csr);

    // ---- layer 1 fused: gather(x·dinv) -> GEMM1 -> BN -> ReLU -> ·dinv ----
    k_fused1<<<NN / 32, 256, 0, stream>>>(x, degoff, csr, dinv,
                                          W1, b1, g1, be1, m1, v1, h1ps);

    // ---- layers 2+3 fused: gather(h1ps) -> GEMM2 -> BN -> ReLU -> GEMM3 -> ·dinv ----
    k_fused23<<<NN / 32, 256, 0, stream>>>(h1ps, degoff, csr, dinv,
                                           W2, b2, g2, be2, m2, v2, W3, hs3);

    // ---- final: gather(hs3) + b3 + ReLU + ·Wo + bo ----
    k_gather_final64<<<gW, 256, 0, stream>>>(hs3, degoff, csr, dinv,
                                             b3, Wo, bo, out);
}

// Round 7
// 606.728 us; speedup vs baseline: 1.4650x; 1.4650x over previous
//
#include <hip/hip_runtime.h>

#define NN 100000
#define NE 1600000
#define NB 391          // ceil(NN/256) blocks for scan
#define BN_EPS 1e-5f

typedef _Float16 h2 __attribute__((ext_vector_type(2)));

static __device__ __forceinline__ unsigned int pack2f(float a, float b) {
    h2 p; p[0] = (_Float16)a; p[1] = (_Float16)b;
    return __builtin_bit_cast(unsigned int, p);
}
static __device__ __forceinline__ float2 unpack2f(unsigned int u) {
    h2 p = __builtin_bit_cast(h2, u);
    return make_float2((float)p[0], (float)p[1]);
}
static __device__ __forceinline__ float unpack1f(unsigned short u) {
    return (float)__builtin_bit_cast(_Float16, u);
}
static __device__ __forceinline__ unsigned short pack1f(float a) {
    return __builtin_bit_cast(unsigned short, (_Float16)a);
}

// ---------------- degree count (int) ----------------
__global__ void k_zero_int(int* __restrict__ p, int n) {
    int i = blockIdx.x * 256 + threadIdx.x;
    if (i < n) p[i] = 0;
}

__global__ void k_count_deg(const int* __restrict__ dst, int* __restrict__ deg) {
    int e = blockIdx.x * 256 + threadIdx.x;
    if (e < NE) atomicAdd(&deg[dst[e]], 1);
}

__global__ void k_dinv(const int* __restrict__ deg, float* __restrict__ dinv) {
    int i = blockIdx.x * 256 + threadIdx.x;
    if (i < NN) dinv[i] = rsqrtf((float)deg[i] + 1.0f);
}

// ---------------- hierarchical exclusive scan ----------------
__global__ __launch_bounds__(256) void k_scan_blocksums(const int* __restrict__ deg,
                                                        int* __restrict__ blk) {
    __shared__ int s[256];
    int i = blockIdx.x * 256 + threadIdx.x;
    s[threadIdx.x] = (i < NN) ? deg[i] : 0;
    __syncthreads();
    for (int off = 128; off > 0; off >>= 1) {
        if (threadIdx.x < off) s[threadIdx.x] += s[threadIdx.x + off];
        __syncthreads();
    }
    if (threadIdx.x == 0) blk[blockIdx.x] = s[0];
}

__global__ __launch_bounds__(512) void k_scan_toplevel(int* __restrict__ blk) {
    __shared__ int s[512];
    int t = threadIdx.x;
    int v = (t < NB) ? blk[t] : 0;
    s[t] = v;
    for (int off = 1; off < 512; off <<= 1) {
        __syncthreads();
        int x = (t >= off) ? s[t - off] : 0;
        __syncthreads();
        s[t] += x;
    }
    __syncthreads();
    if (t < NB) blk[t] = s[t] - v;   // exclusive
}

__global__ __launch_bounds__(256) void k_scan_final(int* __restrict__ degoff,
                                                    const int* __restrict__ blk) {
    __shared__ int s[256];
    int t = threadIdx.x;
    int i = blockIdx.x * 256 + t;
    int v = (i < NN) ? degoff[i] : 0;
    s[t] = v;
    for (int off = 1; off < 256; off <<= 1) {
        __syncthreads();
        int x = (t >= off) ? s[t - off] : 0;
        __syncthreads();
        s[t] += x;
    }
    __syncthreads();
    if (i < NN) degoff[i] = s[t] - v + blk[blockIdx.x];
    if (i == 0) degoff[NN] = NE;
}

// ---------------- CSR fill ----------------
__global__ void k_csr_fill(const int* __restrict__ src, const int* __restrict__ dst,
                           const int* __restrict__ off, int* __restrict__ cur,
                           int* __restrict__ csr) {
    int e = blockIdx.x * 256 + threadIdx.x;
    if (e >= NE) return;
    int n = dst[e];
    int p = atomicAdd(&cur[n], 1);
    csr[off[n] + p] = src[e];
}

// ---------------- weight prep: transpose + fp16 ----------------
// Wt1[128][64], Wt2[128][128], Wt3[64][128]   (all [n][k] fp16)
__global__ void k_prep_w(const float* __restrict__ W1, const float* __restrict__ W2,
                         const float* __restrict__ W3, unsigned short* __restrict__ Wt1,
                         unsigned short* __restrict__ Wt2, unsigned short* __restrict__ Wt3) {
    int i = blockIdx.x * 256 + threadIdx.x;           // 32768 total
    if (i < 8192) {
        int n = i / 64, k = i % 64;
        Wt1[i] = pack1f(W1[k * 128 + n]);
    } else if (i < 24576) {
        int j = i - 8192;
        int n = j / 128, k = j % 128;
        Wt2[j] = pack1f(W2[k * 128 + n]);
    } else if (i < 32768) {
        int j = i - 24576;
        int n = j / 128, k = j % 128;
        Wt3[j] = pack1f(W3[k * 64 + n]);
    }
}

// ---------------- xs = x * dinv[row]  (fp32, 64-wide) ----------------
__global__ void k_scale64(const float* __restrict__ x, const float* __restrict__ dinv,
                          float* __restrict__ xs) {
    int idx = blockIdx.x * 256 + threadIdx.x;      // one float4 per thread
    if (idx >= NN * 16) return;
    int row = idx >> 4;
    float d = dinv[row];
    float4 v = ((const float4*)x)[idx];
    v.x *= d; v.y *= d; v.z *= d; v.w *= d;
    ((float4*)xs)[idx] = v;
}

// ---------------- 64-wide fp32 gather: agg = (sum xs[src] + xs[n]) * dinv[n] ----------------
__global__ __launch_bounds__(256) void k_gather64(
        const float* __restrict__ xs, const int* __restrict__ off,
        const int* __restrict__ csr, const float* __restrict__ dinv,
        float* __restrict__ agg) {
    int n = blockIdx.x * 4 + (threadIdx.x >> 6);
    if (n >= NN) return;
    int lane = threadIdx.x & 63;

    int beg = off[n], end = off[n + 1];
    float a0 = 0.f, a1 = 0.f, a2 = 0.f, a3 = 0.f;
    int e = beg;
    for (; e + 4 <= end; e += 4) {
        int s0 = csr[e], s1 = csr[e + 1], s2 = csr[e + 2], s3 = csr[e + 3];
        a0 += xs[(size_t)s0 * 64 + lane];
        a1 += xs[(size_t)s1 * 64 + lane];
        a2 += xs[(size_t)s2 * 64 + lane];
        a3 += xs[(size_t)s3 * 64 + lane];
    }
    for (; e < end; ++e) a0 += xs[(size_t)csr[e] * 64 + lane];

    agg[(size_t)n * 64 + lane] =
        (a0 + a1 + a2 + a3 + xs[(size_t)n * 64 + lane]) * dinv[n];
}

// ---------------- 128-wide gather, fp16 in / fp32 out ----------------
__global__ __launch_bounds__(256) void k_gather128_f16(
        const unsigned short* __restrict__ h1, const int* __restrict__ off,
        const int* __restrict__ csr, const float* __restrict__ dinv,
        float* __restrict__ agg) {
    int n = blockIdx.x * 4 + (threadIdx.x >> 6);
    if (n >= NN) return;
    int lane = threadIdx.x & 63;
    const unsigned int* h = (const unsigned int*)h1;   // half2 per lane, row stride 64

    int beg = off[n], end = off[n + 1];
    float ax = 0.f, ay = 0.f, bx = 0.f, by = 0.f;
    float cx = 0.f, cy = 0.f, dx = 0.f, dy = 0.f;
    int e = beg;
    for (; e + 4 <= end; e += 4) {
        int s0 = csr[e], s1 = csr[e + 1], s2 = csr[e + 2], s3 = csr[e + 3];
        float2 u0 = unpack2f(h[(size_t)s0 * 64 + lane]);
        float2 u1 = unpack2f(h[(size_t)s1 * 64 + lane]);
        float2 u2 = unpack2f(h[(size_t)s2 * 64 + lane]);
        float2 u3 = unpack2f(h[(size_t)s3 * 64 + lane]);
        ax += u0.x; ay += u0.y;
        bx += u1.x; by += u1.y;
        cx += u2.x; cy += u2.y;
        dx += u3.x; dy += u3.y;
    }
    for (; e < end; ++e) {
        float2 u0 = unpack2f(h[(size_t)csr[e] * 64 + lane]);
        ax += u0.x; ay += u0.y;
    }
    float2 self = unpack2f(h[(size_t)n * 64 + lane]);
    float dn = dinv[n];
    float2 o;
    o.x = (ax + bx + cx + dx + self.x) * dn;
    o.y = (ay + by + cy + dy + self.y) * dn;
    ((float2*)agg)[(size_t)n * 64 + lane] = o;
}

// ---------------- GEMM: A fp32 (LDS, swizzled), W fp16 (LDS, swizzled), 8xCT tile ----
// EPI 1: BN+ReLU+*dinv -> fp16 out. EPI 2: BN+ReLU -> fp32 out. EPI 3: *dinv -> fp16 out.
template <int K, int M, int CT, int NCHUNK, int EPI>
__global__ __launch_bounds__(256, 2) void k_gemm_f16w(
        const float* __restrict__ A, const unsigned short* __restrict__ Wt,
        const float* __restrict__ dinv, const float* __restrict__ bias,
        const float* __restrict__ g, const float* __restrict__ be,
        const float* __restrict__ mn, const float* __restrict__ vr,
        void* __restrict__ outp) {
    constexpr int KC  = K / NCHUNK;        // k-chunk (64)
    constexpr int AC4 = KC / 4;            // A 16B-chunks per row (16)
    constexpr int WC8 = K / 8;             // W 16B-chunks per row
    __shared__ __align__(16) float          sA[128 * KC];
    __shared__ __align__(16) unsigned short sW[M * K];

    int tid  = threadIdx.x;
    int n0   = blockIdx.x * 128;
    int rt   = tid >> 4;                   // 0..15, 8 rows each
    int ctid = tid & 15;                   // 0..15, CT cols each

    // stage W fully (swizzled 16B chunks)
    {
        const uint4* s = (const uint4*)Wt;
        uint4* d = (uint4*)sW;
        for (int i = tid; i < M * WC8; i += 256) {
            int r = i / WC8, c = i % WC8;
            d[r * WC8 + (c ^ ((r >> 3) & 7))] = s[i];
        }
    }
    // stage A chunk 0
    auto stageA = [&](int kc0) {
        uint4* d = (uint4*)sA;
        for (int i = tid; i < 128 * AC4; i += 256) {
            int r = i / AC4, c = i % AC4;
            int gr = n0 + r; if (gr >= NN) gr = NN - 1;
            uint4 v = *(const uint4*)(A + (size_t)gr * K + kc0 + c * 4);
            d[r * AC4 + (c ^ ((r >> 3) & 7))] = v;
        }
    };
    stageA(0);
    __syncthreads();

    float acc[8][CT];
#pragma unroll
    for (int jr = 0; jr < 8; ++jr)
#pragma unroll
        for (int jc = 0; jc < CT; ++jc) acc[jr][jc] = 0.f;

    for (int ch = 0; ch < NCHUNK; ++ch) {
        if (ch > 0) {
            __syncthreads();
            stageA(ch * KC);
            __syncthreads();
        }
        for (int k8 = 0; k8 < KC / 8; ++k8) {
            float af[8][8];
            const float4* a4 = (const float4*)sA;
#pragma unroll
            for (int jr = 0; jr < 8; ++jr) {
                int r = rt * 8 + jr;
                float4 f0 = a4[r * AC4 + ((k8 * 2 + 0) ^ (rt & 7))];
                float4 f1 = a4[r * AC4 + ((k8 * 2 + 1) ^ (rt & 7))];
                af[jr][0] = f0.x; af[jr][1] = f0.y; af[jr][2] = f0.z; af[jr][3] = f0.w;
                af[jr][4] = f1.x; af[jr][5] = f1.y; af[jr][6] = f1.z; af[jr][7] = f1.w;
            }
            int k8g = ch * (KC / 8) + k8;
#pragma unroll
            for (int jc = 0; jc < CT; ++jc) {
                int cc = ctid * CT + jc;
                uint4 wv = ((const uint4*)sW)[cc * WC8 + (k8g ^ ((cc >> 3) & 7))];
                float wf[8];
                {
                    h2 p;
                    p = __builtin_bit_cast(h2, wv.x); wf[0] = (float)p[0]; wf[1] = (float)p[1];
                    p = __builtin_bit_cast(h2, wv.y); wf[2] = (float)p[0]; wf[3] = (float)p[1];
                    p = __builtin_bit_cast(h2, wv.z); wf[4] = (float)p[0]; wf[5] = (float)p[1];
                    p = __builtin_bit_cast(h2, wv.w); wf[6] = (float)p[0]; wf[7] = (float)p[1];
                }
#pragma unroll
                for (int jr = 0; jr < 8; ++jr)
#pragma unroll
                    for (int q = 0; q < 8; ++q)
                        acc[jr][jc] = fmaf(af[jr][q], wf[q], acc[jr][jc]);
            }
        }
    }

    int c0 = ctid * CT;
    if constexpr (EPI == 1 || EPI == 2) {
        float sc[CT], sh[CT];
#pragma unroll
        for (int q = 0; q < CT; ++q) {
            int c = c0 + q;
            float s = g[c] * rsqrtf(vr[c] + BN_EPS);
            sc[q] = s;
            sh[q] = (bias[c] - mn[c]) * s + be[c];
        }
#pragma unroll
        for (int jr = 0; jr < 8; ++jr) {
            int gr = n0 + rt * 8 + jr;
            if (gr < NN) {
                float vv[CT];
#pragma unroll
                for (int q = 0; q < CT; ++q)
                    vv[q] = fmaxf(acc[jr][q] * sc[q] + sh[q], 0.f);
                if constexpr (EPI == 1) {
                    float d = dinv[gr];
                    uint4 o;
                    o.x = pack2f(vv[0] * d, vv[1] * d);
                    o.y = pack2f(vv[2] * d, vv[3] * d);
                    o.z = pack2f(vv[4] * d, vv[5] * d);
                    o.w = pack2f(vv[6] * d, vv[7] * d);
                    *(uint4*)((unsigned short*)outp + (size_t)gr * M + c0) = o;
                } else {
                    float* op = (float*)outp + (size_t)gr * M + c0;
                    float4 o0, o1;
                    o0.x = vv[0]; o0.y = vv[1]; o0.z = vv[2]; o0.w = vv[3];
                    o1.x = vv[4]; o1.y = vv[5]; o1.z = vv[6]; o1.w = vv[7];
                    ((float4*)op)[0] = o0;
                    ((float4*)op)[1] = o1;
                }
            }
        }
    } else {   // EPI == 3, CT == 4
#pragma unroll
        for (int jr = 0; jr < 8; ++jr) {
            int gr = n0 + rt * 8 + jr;
            if (gr < NN) {
                float d = dinv[gr];
                uint2 o;
                o.x = pack2f(acc[jr][0] * d, acc[jr][1] * d);
                o.y = pack2f(acc[jr][2] * d, acc[jr][3] * d);
                *(uint2*)((unsigned short*)outp + (size_t)gr * M + c0) = o;
            }
        }
    }
}

// ---------------- final: gather fp16 + b3 + ReLU + (·Wo + bo) ----------------
__global__ __launch_bounds__(256) void k_gather_final_f16(
        const unsigned short* __restrict__ hs, const int* __restrict__ off,
        const int* __restrict__ csr, const float* __restrict__ dinv,
        const float* __restrict__ b, const float* __restrict__ Wo,
        const float* __restrict__ bo, float* __restrict__ out) {
    int n = blockIdx.x * 4 + (threadIdx.x >> 6);
    if (n >= NN) return;
    int lane = threadIdx.x & 63;

    int beg = off[n], end = off[n + 1];
    float a0 = 0.f, a1 = 0.f, a2 = 0.f, a3 = 0.f;
    int e = beg;
    for (; e + 4 <= end; e += 4) {
        int s0 = csr[e], s1 = csr[e + 1], s2 = csr[e + 2], s3 = csr[e + 3];
        a0 += unpack1f(hs[(size_t)s0 * 64 + lane]);
        a1 += unpack1f(hs[(size_t)s1 * 64 + lane]);
        a2 += unpack1f(hs[(size_t)s2 * 64 + lane]);
        a3 += unpack1f(hs[(size_t)s3 * 64 + lane]);
    }
    for (; e < end; ++e) a0 += unpack1f(hs[(size_t)csr[e] * 64 + lane]);

    float val = (a0 + a1 + a2 + a3 + unpack1f(hs[(size_t)n * 64 + lane])) * dinv[n]
                + b[lane];
    val = fmaxf(val, 0.f) * Wo[lane];
#pragma unroll
    for (int o = 32; o > 0; o >>= 1) val += __shfl_down(val, o, 64);
    if (lane == 0) out[n] = val + bo[0];
}

extern "C" void kernel_launch(void* const* d_in, const int* in_sizes, int n_in,
                              void* d_out, int out_size, void* d_ws, size_t ws_size,
                              hipStream_t stream) {
    const float* x   = (const float*)d_in[0];
    const int*   ei  = (const int*)d_in[1];
    const int*   src = ei;
    const int*   dst = ei + NE;
    const float* W1  = (const float*)d_in[2];
    const float* b1  = (const float*)d_in[3];
    const float* g1  = (const float*)d_in[4];
    const float* be1 = (const float*)d_in[5];
    const float* m1  = (const float*)d_in[6];
    const float* v1  = (const float*)d_in[7];
    const float* W2  = (const float*)d_in[8];
    const float* b2  = (const float*)d_in[9];
    const float* g2  = (const float*)d_in[10];
    const float* be2 = (const float*)d_in[11];
    const float* m2  = (const float*)d_in[12];
    const float* v2  = (const float*)d_in[13];
    const float* W3  = (const float*)d_in[14];
    const float* b3  = (const float*)d_in[15];
    const float* Wo  = (const float*)d_in[16];
    const float* bo  = (const float*)d_in[17];
    float* out = (float*)d_out;

    char* ws = (char*)d_ws;
    float* dinv   = (float*)(ws + 0);              // 400,000 B
    int*   degoff = (int*)(ws + 400000);           // (N+1) ints
    int*   cur    = (int*)(ws + 800032);           // 400,000 B (reused for Wt after csr)
    int*   blk    = (int*)(ws + 1200032);          // NB ints
    int*   csr    = (int*)(ws + 1201600);          // 6,400,000 B -> 7,601,600
    // Wt tables live in the dead 'cur' region after k_csr_fill:
    unsigned short* Wt1 = (unsigned short*)(ws + 800032);   // 16,384 B
    unsigned short* Wt2 = (unsigned short*)(ws + 816416);   // 32,768 B
    unsigned short* Wt3 = (unsigned short*)(ws + 849184);   // 16,384 B  (end 865,568 < 1,200,032)
    // two 51.2 MB slots, lifetimes alternate:
    char* S1 = ws + 7601600;                       // xs(f32) -> h1ps(f16) -> h2p(f32)
    char* S2 = ws + 58801600;                      // aggX(f32) -> aggH1(f32) -> hs3(f16)

    float*          xs    = (float*)S1;
    unsigned short* h1ps  = (unsigned short*)S1;
    float*          h2p   = (float*)S1;
    float*          aggX  = (float*)S2;
    float*          aggH1 = (float*)S2;
    unsigned short* hs3   = (unsigned short*)S2;

    int gN = (NN + 255) / 256;
    int gE = (NE + 255) / 256;
    int gW = (NN + 3) / 4;
    int gG = (NN + 127) / 128;

    // ---- CSR build + dinv ----
    k_zero_int<<<gN, 256, 0, stream>>>(degoff, NN);
    k_zero_int<<<gN, 256, 0, stream>>>(cur, NN);
    k_count_deg<<<gE, 256, 0, stream>>>(dst, degoff);
    k_dinv<<<gN, 256, 0, stream>>>(degoff, dinv);
    k_scan_blocksums<<<NB, 256, 0, stream>>>(degoff, blk);
    k_scan_toplevel<<<1, 512, 0, stream>>>(blk);
    k_scan_final<<<NB, 256, 0, stream>>>(degoff, blk);
    k_csr_fill<<<gE, 256, 0, stream>>>(src, dst, degoff, cur, csr);

    // ---- weights -> transposed fp16 (overwrites 'cur', safe after csr_fill) ----
    k_prep_w<<<128, 256, 0, stream>>>(W1, W2, W3, Wt1, Wt2, Wt3);

    // ---- layer 1: xs = x*dinv ; gather ; GEMM1 + BN + ReLU + *dinv -> h1ps(f16) ----
    k_scale64<<<(NN * 16 + 255) / 256, 256, 0, stream>>>(x, dinv, xs);
    k_gather64<<<gW, 256, 0, stream>>>(xs, degoff, csr, dinv, aggX);
    k_gemm_f16w<64, 128, 8, 1, 1><<<gG, 256, 0, stream>>>(
        aggX, Wt1, dinv, b1, g1, be1, m1, v1, (void*)h1ps);

    // ---- layer 2: gather(h1ps f16) -> aggH1(f32) ; GEMM2 + BN + ReLU -> h2p(f32) ----
    k_gather128_f16<<<gW, 256, 0, stream>>>(h1ps, degoff, csr, dinv, aggH1);
    k_gemm_f16w<128, 128, 8, 2, 2><<<gG, 256, 0, stream>>>(
        aggH1, Wt2, dinv, b2, g2, be2, m2, v2, (void*)h2p);

    // ---- layer 3: GEMM3 (*dinv) -> hs3(f16) ; final gather + dot ----
    k_gemm_f16w<128, 64, 4, 2, 3><<<gG, 256, 0, stream>>>(
        h2p, Wt3, dinv, nullptr, nullptr, nullptr, nullptr, nullptr, (void*)hs3);
    k_gather_final_f16<<<gW, 256, 0, stream>>>(hs3, degoff, csr, dinv,
                                               b3, Wo, bo, out);
}

// Round 8
// 481.037 us; speedup vs baseline: 1.8479x; 1.2613x over previous
//
#include <hip/hip_runtime.h>

#define NN 100000
#define NE 1600000
#define NB 391          // ceil(NN/256) blocks for scan
#define BN_EPS 1e-5f

typedef _Float16 h2 __attribute__((ext_vector_type(2)));

static __device__ __forceinline__ unsigned int pack2f(float a, float b) {
    h2 p; p[0] = (_Float16)a; p[1] = (_Float16)b;
    return __builtin_bit_cast(unsigned int, p);
}
static __device__ __forceinline__ float2 unpack2f(unsigned int u) {
    h2 p = __builtin_bit_cast(h2, u);
    return make_float2((float)p[0], (float)p[1]);
}
static __device__ __forceinline__ float unpack1f(unsigned short u) {
    return (float)__builtin_bit_cast(_Float16, u);
}
static __device__ __forceinline__ unsigned short pack1f(float a) {
    return __builtin_bit_cast(unsigned short, (_Float16)a);
}

// ---------------- helpers ----------------
__global__ void k_zero_int(int* __restrict__ p, int n) {
    int i = blockIdx.x * 256 + threadIdx.x;
    if (i < n) p[i] = 0;
}

// count degree AND record each edge's rank within its dst node (atomic return).
__global__ void k_count_rank(const int* __restrict__ dst, int* __restrict__ deg,
                             int* __restrict__ rank) {
    int e = blockIdx.x * 256 + threadIdx.x;
    if (e < NE) rank[e] = atomicAdd(&deg[dst[e]], 1);
}

// ---------------- hierarchical exclusive scan ----------------
__global__ __launch_bounds__(256) void k_scan_blocksums(const int* __restrict__ deg,
                                                        int* __restrict__ blk) {
    __shared__ int s[256];
    int i = blockIdx.x * 256 + threadIdx.x;
    s[threadIdx.x] = (i < NN) ? deg[i] : 0;
    __syncthreads();
    for (int off = 128; off > 0; off >>= 1) {
        if (threadIdx.x < off) s[threadIdx.x] += s[threadIdx.x + off];
        __syncthreads();
    }
    if (threadIdx.x == 0) blk[blockIdx.x] = s[0];
}

__global__ __launch_bounds__(512) void k_scan_toplevel(int* __restrict__ blk) {
    __shared__ int s[512];
    int t = threadIdx.x;
    int v = (t < NB) ? blk[t] : 0;
    s[t] = v;
    for (int off = 1; off < 512; off <<= 1) {
        __syncthreads();
        int x = (t >= off) ? s[t - off] : 0;
        __syncthreads();
        s[t] += x;
    }
    __syncthreads();
    if (t < NB) blk[t] = s[t] - v;   // exclusive
}

// scan deg -> offsets in place, AND compute dinv from the pre-scan deg value.
__global__ __launch_bounds__(256) void k_scan_final(int* __restrict__ degoff,
                                                    const int* __restrict__ blk,
                                                    float* __restrict__ dinv) {
    __shared__ int s[256];
    int t = threadIdx.x;
    int i = blockIdx.x * 256 + t;
    int v = (i < NN) ? degoff[i] : 0;
    s[t] = v;
    for (int off = 1; off < 256; off <<= 1) {
        __syncthreads();
        int x = (t >= off) ? s[t - off] : 0;
        __syncthreads();
        s[t] += x;
    }
    __syncthreads();
    if (i < NN) {
        degoff[i] = s[t] - v + blk[blockIdx.x];
        dinv[i] = rsqrtf((float)v + 1.0f);
    }
    if (i == 0) degoff[NN] = NE;
}

// ---------------- mega: CSR fill (no atomics) + weight prep + xs scale ----------------
#define FILL_BLOCKS 6250          // NE / 256
#define PREP_BLOCKS 128           // 32768 / 256
#define SCALE_BLOCKS 3125         // NN*8 / 256
__global__ __launch_bounds__(256) void k_mega(
        const int* __restrict__ src, const int* __restrict__ dst,
        const int* __restrict__ rank, const int* __restrict__ off,
        int* __restrict__ csr,
        const float* __restrict__ W1, const float* __restrict__ W2,
        const float* __restrict__ W3, unsigned short* __restrict__ Wt1,
        unsigned short* __restrict__ Wt2, unsigned short* __restrict__ Wt3,
        const float* __restrict__ x, const float* __restrict__ dinv,
        unsigned short* __restrict__ xs) {
    int b = blockIdx.x;
    if (b < FILL_BLOCKS) {
        int e = b * 256 + threadIdx.x;
        int n = dst[e];
        csr[off[n] + rank[e]] = src[e];
    } else if (b < FILL_BLOCKS + PREP_BLOCKS) {
        int i = (b - FILL_BLOCKS) * 256 + threadIdx.x;   // 0..32767
        if (i < 8192) {
            int n = i / 64, k = i % 64;
            Wt1[i] = pack1f(W1[k * 128 + n]);
        } else if (i < 24576) {
            int j = i - 8192;
            int n = j / 128, k = j % 128;
            Wt2[j] = pack1f(W2[k * 128 + n]);
        } else {
            int j = i - 24576;
            int n = j / 128, k = j % 128;
            Wt3[j] = pack1f(W3[k * 64 + n]);
        }
    } else {
        int i = (b - FILL_BLOCKS - PREP_BLOCKS) * 256 + threadIdx.x;  // 0..799999
        int row = i >> 3, c8 = i & 7;                     // 8 cols per thread
        float d = dinv[row];
        const float4* xp = (const float4*)(x + (size_t)row * 64 + c8 * 8);
        float4 f0 = xp[0], f1 = xp[1];
        uint4 o;
        o.x = pack2f(f0.x * d, f0.y * d);
        o.y = pack2f(f0.z * d, f0.w * d);
        o.z = pack2f(f1.x * d, f1.y * d);
        o.w = pack2f(f1.z * d, f1.w * d);
        *(uint4*)(xs + (size_t)row * 64 + c8 * 8) = o;
    }
}

// ---------------- 64-wide fp16 gather: agg = (sum xs[src] + xs[n]) * dinv[n] ----------------
__global__ __launch_bounds__(256) void k_gather64_f16(
        const unsigned short* __restrict__ xs, const int* __restrict__ off,
        const int* __restrict__ csr, const float* __restrict__ dinv,
        float* __restrict__ agg) {
    int n = blockIdx.x * 4 + (threadIdx.x >> 6);
    if (n >= NN) return;
    int lane = threadIdx.x & 63;

    int beg = off[n], end = off[n + 1];
    float a0 = 0.f, a1 = 0.f, a2 = 0.f, a3 = 0.f;
    int e = beg;
    for (; e + 4 <= end; e += 4) {
        int s0 = csr[e], s1 = csr[e + 1], s2 = csr[e + 2], s3 = csr[e + 3];
        a0 += unpack1f(xs[(size_t)s0 * 64 + lane]);
        a1 += unpack1f(xs[(size_t)s1 * 64 + lane]);
        a2 += unpack1f(xs[(size_t)s2 * 64 + lane]);
        a3 += unpack1f(xs[(size_t)s3 * 64 + lane]);
    }
    for (; e < end; ++e) a0 += unpack1f(xs[(size_t)csr[e] * 64 + lane]);

    agg[(size_t)n * 64 + lane] =
        (a0 + a1 + a2 + a3 + unpack1f(xs[(size_t)n * 64 + lane])) * dinv[n];
}

// ---------------- 128-wide gather, fp16 in / fp32 out ----------------
__global__ __launch_bounds__(256) void k_gather128_f16(
        const unsigned short* __restrict__ h1, const int* __restrict__ off,
        const int* __restrict__ csr, const float* __restrict__ dinv,
        float* __restrict__ agg) {
    int n = blockIdx.x * 4 + (threadIdx.x >> 6);
    if (n >= NN) return;
    int lane = threadIdx.x & 63;
    const unsigned int* h = (const unsigned int*)h1;   // half2 per lane, row stride 64

    int beg = off[n], end = off[n + 1];
    float ax = 0.f, ay = 0.f, bx = 0.f, by = 0.f;
    float cx = 0.f, cy = 0.f, dx = 0.f, dy = 0.f;
    int e = beg;
    for (; e + 4 <= end; e += 4) {
        int s0 = csr[e], s1 = csr[e + 1], s2 = csr[e + 2], s3 = csr[e + 3];
        float2 u0 = unpack2f(h[(size_t)s0 * 64 + lane]);
        float2 u1 = unpack2f(h[(size_t)s1 * 64 + lane]);
        float2 u2 = unpack2f(h[(size_t)s2 * 64 + lane]);
        float2 u3 = unpack2f(h[(size_t)s3 * 64 + lane]);
        ax += u0.x; ay += u0.y;
        bx += u1.x; by += u1.y;
        cx += u2.x; cy += u2.y;
        dx += u3.x; dy += u3.y;
    }
    for (; e < end; ++e) {
        float2 u0 = unpack2f(h[(size_t)csr[e] * 64 + lane]);
        ax += u0.x; ay += u0.y;
    }
    float2 self = unpack2f(h[(size_t)n * 64 + lane]);
    float dn = dinv[n];
    float2 o;
    o.x = (ax + bx + cx + dx + self.x) * dn;
    o.y = (ay + by + cy + dy + self.y) * dn;
    ((float2*)agg)[(size_t)n * 64 + lane] = o;
}

// ---------------- GEMM: A fp32 (LDS, swizzled), W fp16 (LDS, swizzled), 8xCT tile ----
// EPI 1: BN+ReLU+*dinv -> fp16 out. EPI 2: BN+ReLU -> fp32 out. EPI 3: *dinv -> fp16 out.
template <int K, int M, int CT, int NCHUNK, int EPI>
__global__ __launch_bounds__(256, 2) void k_gemm_f16w(
        const float* __restrict__ A, const unsigned short* __restrict__ Wt,
        const float* __restrict__ dinv, const float* __restrict__ bias,
        const float* __restrict__ g, const float* __restrict__ be,
        const float* __restrict__ mn, const float* __restrict__ vr,
        void* __restrict__ outp) {
    constexpr int KC  = K / NCHUNK;        // k-chunk (64)
    constexpr int AC4 = KC / 4;            // A 16B-chunks per row (16)
    constexpr int WC8 = K / 8;             // W 16B-chunks per row
    __shared__ __align__(16) float          sA[128 * KC];
    __shared__ __align__(16) unsigned short sW[M * K];

    int tid  = threadIdx.x;
    int n0   = blockIdx.x * 128;
    int rt   = tid >> 4;                   // 0..15, 8 rows each
    int ctid = tid & 15;                   // 0..15, CT cols each

    // stage W fully (swizzled 16B chunks)
    {
        const uint4* s = (const uint4*)Wt;
        uint4* d = (uint4*)sW;
        for (int i = tid; i < M * WC8; i += 256) {
            int r = i / WC8, c = i % WC8;
            d[r * WC8 + (c ^ ((r >> 3) & 7))] = s[i];
        }
    }
    // stage A chunk 0
    auto stageA = [&](int kc0) {
        uint4* d = (uint4*)sA;
        for (int i = tid; i < 128 * AC4; i += 256) {
            int r = i / AC4, c = i % AC4;
            int gr = n0 + r; if (gr >= NN) gr = NN - 1;
            uint4 v = *(const uint4*)(A + (size_t)gr * K + kc0 + c * 4);
            d[r * AC4 + (c ^ ((r >> 3) & 7))] = v;
        }
    };
    stageA(0);
    __syncthreads();

    float acc[8][CT];
#pragma unroll
    for (int jr = 0; jr < 8; ++jr)
#pragma unroll
        for (int jc = 0; jc < CT; ++jc) acc[jr][jc] = 0.f;

    for (int ch = 0; ch < NCHUNK; ++ch) {
        if (ch > 0) {
            __syncthreads();
            stageA(ch * KC);
            __syncthreads();
        }
        for (int k8 = 0; k8 < KC / 8; ++k8) {
            float af[8][8];
            const float4* a4 = (const float4*)sA;
#pragma unroll
            for (int jr = 0; jr < 8; ++jr) {
                int r = rt * 8 + jr;
                float4 f0 = a4[r * AC4 + ((k8 * 2 + 0) ^ (rt & 7))];
                float4 f1 = a4[r * AC4 + ((k8 * 2 + 1) ^ (rt & 7))];
                af[jr][0] = f0.x; af[jr][1] = f0.y; af[jr][2] = f0.z; af[jr][3] = f0.w;
                af[jr][4] = f1.x; af[jr][5] = f1.y; af[jr][6] = f1.z; af[jr][7] = f1.w;
            }
            int k8g = ch * (KC / 8) + k8;
#pragma unroll
            for (int jc = 0; jc < CT; ++jc) {
                int cc = ctid * CT + jc;
                uint4 wv = ((const uint4*)sW)[cc * WC8 + (k8g ^ ((cc >> 3) & 7))];
                float wf[8];
                {
                    h2 p;
                    p = __builtin_bit_cast(h2, wv.x); wf[0] = (float)p[0]; wf[1] = (float)p[1];
                    p = __builtin_bit_cast(h2, wv.y); wf[2] = (float)p[0]; wf[3] = (float)p[1];
                    p = __builtin_bit_cast(h2, wv.z); wf[4] = (float)p[0]; wf[5] = (float)p[1];
                    p = __builtin_bit_cast(h2, wv.w); wf[6] = (float)p[0]; wf[7] = (float)p[1];
                }
#pragma unroll
                for (int jr = 0; jr < 8; ++jr)
#pragma unroll
                    for (int q = 0; q < 8; ++q)
                        acc[jr][jc] = fmaf(af[jr][q], wf[q], acc[jr][jc]);
            }
        }
    }

    int c0 = ctid * CT;
    if constexpr (EPI == 1 || EPI == 2) {
        float sc[CT], sh[CT];
#pragma unroll
        for (int q = 0; q < CT; ++q) {
            int c = c0 + q;
            float s = g[c] * rsqrtf(vr[c] + BN_EPS);
            sc[q] = s;
            sh[q] = (bias[c] - mn[c]) * s + be[c];
        }
#pragma unroll
        for (int jr = 0; jr < 8; ++jr) {
            int gr = n0 + rt * 8 + jr;
            if (gr < NN) {
                float vv[CT];
#pragma unroll
                for (int q = 0; q < CT; ++q)
                    vv[q] = fmaxf(acc[jr][q] * sc[q] + sh[q], 0.f);
                if constexpr (EPI == 1) {
                    float d = dinv[gr];
                    uint4 o;
                    o.x = pack2f(vv[0] * d, vv[1] * d);
                    o.y = pack2f(vv[2] * d, vv[3] * d);
                    o.z = pack2f(vv[4] * d, vv[5] * d);
                    o.w = pack2f(vv[6] * d, vv[7] * d);
                    *(uint4*)((unsigned short*)outp + (size_t)gr * M + c0) = o;
                } else {
                    float* op = (float*)outp + (size_t)gr * M + c0;
                    float4 o0, o1;
                    o0.x = vv[0]; o0.y = vv[1]; o0.z = vv[2]; o0.w = vv[3];
                    o1.x = vv[4]; o1.y = vv[5]; o1.z = vv[6]; o1.w = vv[7];
                    ((float4*)op)[0] = o0;
                    ((float4*)op)[1] = o1;
                }
            }
        }
    } else {   // EPI == 3, CT == 4
#pragma unroll
        for (int jr = 0; jr < 8; ++jr) {
            int gr = n0 + rt * 8 + jr;
            if (gr < NN) {
                float d = dinv[gr];
                uint2 o;
                o.x = pack2f(acc[jr][0] * d, acc[jr][1] * d);
                o.y = pack2f(acc[jr][2] * d, acc[jr][3] * d);
                *(uint2*)((unsigned short*)outp + (size_t)gr * M + c0) = o;
            }
        }
    }
}

// ---------------- final: gather fp16 + b3 + ReLU + (·Wo + bo) ----------------
__global__ __launch_bounds__(256) void k_gather_final_f16(
        const unsigned short* __restrict__ hs, const int* __restrict__ off,
        const int* __restrict__ csr, const float* __restrict__ dinv,
        const float* __restrict__ b, const float* __restrict__ Wo,
        const float* __restrict__ bo, float* __restrict__ out) {
    int n = blockIdx.x * 4 + (threadIdx.x >> 6);
    if (n >= NN) return;
    int lane = threadIdx.x & 63;

    int beg = off[n], end = off[n + 1];
    float a0 = 0.f, a1 = 0.f, a2 = 0.f, a3 = 0.f;
    int e = beg;
    for (; e + 4 <= end; e += 4) {
        int s0 = csr[e], s1 = csr[e + 1], s2 = csr[e + 2], s3 = csr[e + 3];
        a0 += unpack1f(hs[(size_t)s0 * 64 + lane]);
        a1 += unpack1f(hs[(size_t)s1 * 64 + lane]);
        a2 += unpack1f(hs[(size_t)s2 * 64 + lane]);
        a3 += unpack1f(hs[(size_t)s3 * 64 + lane]);
    }
    for (; e < end; ++e) a0 += unpack1f(hs[(size_t)csr[e] * 64 + lane]);

    float val = (a0 + a1 + a2 + a3 + unpack1f(hs[(size_t)n * 64 + lane])) * dinv[n]
                + b[lane];
    val = fmaxf(val, 0.f) * Wo[lane];
#pragma unroll
    for (int o = 32; o > 0; o >>= 1) val += __shfl_down(val, o, 64);
    if (lane == 0) out[n] = val + bo[0];
}

extern "C" void kernel_launch(void* const* d_in, const int* in_sizes, int n_in,
                              void* d_out, int out_size, void* d_ws, size_t ws_size,
                              hipStream_t stream) {
    const float* x   = (const float*)d_in[0];
    const int*   ei  = (const int*)d_in[1];
    const int*   src = ei;
    const int*   dst = ei + NE;
    const float* W1  = (const float*)d_in[2];
    const float* b1  = (const float*)d_in[3];
    const float* g1  = (const float*)d_in[4];
    const float* be1 = (const float*)d_in[5];
    const float* m1  = (const float*)d_in[6];
    const float* v1  = (const float*)d_in[7];
    const float* W2  = (const float*)d_in[8];
    const float* b2  = (const float*)d_in[9];
    const float* g2  = (const float*)d_in[10];
    const float* be2 = (const float*)d_in[11];
    const float* m2  = (const float*)d_in[12];
    const float* v2  = (const float*)d_in[13];
    const float* W3  = (const float*)d_in[14];
    const float* b3  = (const float*)d_in[15];
    const float* Wo  = (const float*)d_in[16];
    const float* bo  = (const float*)d_in[17];
    float* out = (float*)d_out;

    char* ws = (char*)d_ws;
    float* dinv   = (float*)(ws + 0);              // 400,000 B
    int*   degoff = (int*)(ws + 400032);           // (N+1) ints -> 800,036
    int*   blk    = (int*)(ws + 800064);           // NB ints -> 801,628
    unsigned short* Wt1 = (unsigned short*)(ws + 801664);   // 16,384 B
    unsigned short* Wt2 = (unsigned short*)(ws + 818048);   // 32,768 B
    unsigned short* Wt3 = (unsigned short*)(ws + 850816);   // 16,384 B -> 867,200
    int*   csr    = (int*)(ws + 867200);           // 6,400,000 B -> 7,267,200
    char*  S1     = ws + 7267200;                  // 51.2 MB: xs(f16)->h1ps(f16)->h2p(f32)
    char*  S2     = ws + 58467200;                 // 51.2 MB: rank->aggX->aggH1->hs3

    unsigned short* xs    = (unsigned short*)S1;
    unsigned short* h1ps  = (unsigned short*)S1;
    float*          h2p   = (float*)S1;
    int*            rank  = (int*)S2;
    float*          aggX  = (float*)S2;
    float*          aggH1 = (float*)S2;
    unsigned short* hs3   = (unsigned short*)S2;

    int gN = (NN + 255) / 256;
    int gE = (NE + 255) / 256;
    int gW = (NN + 3) / 4;
    int gG = (NN + 127) / 128;

    // ---- CSR build (rank trick: single atomic pass) + dinv ----
    k_zero_int<<<gN, 256, 0, stream>>>(degoff, NN);
    k_count_rank<<<gE, 256, 0, stream>>>(dst, degoff, rank);
    k_scan_blocksums<<<NB, 256, 0, stream>>>(degoff, blk);
    k_scan_toplevel<<<1, 512, 0, stream>>>(blk);
    k_scan_final<<<NB, 256, 0, stream>>>(degoff, blk, dinv);

    // ---- mega: CSR fill (atomic-free) + weight fp16 transpose + xs = x*dinv (fp16) ----
    k_mega<<<FILL_BLOCKS + PREP_BLOCKS + SCALE_BLOCKS, 256, 0, stream>>>(
        src, dst, rank, degoff, csr, W1, W2, W3, Wt1, Wt2, Wt3, x, dinv, xs);

    // ---- layer 1: gather(xs f16) ; GEMM1 + BN + ReLU + *dinv -> h1ps(f16) ----
    k_gather64_f16<<<gW, 256, 0, stream>>>(xs, degoff, csr, dinv, aggX);
    k_gemm_f16w<64, 128, 8, 1, 1><<<gG, 256, 0, stream>>>(
        aggX, Wt1, dinv, b1, g1, be1, m1, v1, (void*)h1ps);

    // ---- layer 2: gather(h1ps f16) -> aggH1(f32) ; GEMM2 + BN + ReLU -> h2p(f32) ----
    k_gather128_f16<<<gW, 256, 0, stream>>>(h1ps, degoff, csr, dinv, aggH1);
    k_gemm_f16w<128, 128, 8, 2, 2><<<gG, 256, 0, stream>>>(
        aggH1, Wt2, dinv, b2, g2, be2, m2, v2, (void*)h2p);

    // ---- layer 3: GEMM3 (*dinv) -> hs3(f16) ; final gather + dot ----
    k_gemm_f16w<128, 64, 4, 2, 3><<<gG, 256, 0, stream>>>(
        h2p, Wt3, dinv, nullptr, nullptr, nullptr, nullptr, nullptr, (void*)hs3);
    k_gather_final_f16<<<gW, 256, 0, stream>>>(hs3, degoff, csr, dinv,
                                               b3, Wo, bo, out);
}

// Round 9
// 363.979 us; speedup vs baseline: 2.4421x; 1.3216x over previous
//
#include <hip/hip_runtime.h>

#define NN 100000
#define NE 1600000
#define NB 391          // ceil(NN/256) blocks for scan
#define BN_EPS 1e-5f

typedef _Float16 h2 __attribute__((ext_vector_type(2)));
typedef _Float16 f16x8 __attribute__((ext_vector_type(8)));
typedef float f32x4 __attribute__((ext_vector_type(4)));

static __device__ __forceinline__ unsigned int pack2f(float a, float b) {
    h2 p; p[0] = (_Float16)a; p[1] = (_Float16)b;
    return __builtin_bit_cast(unsigned int, p);
}
static __device__ __forceinline__ float2 unpack2f(unsigned int u) {
    h2 p = __builtin_bit_cast(h2, u);
    return make_float2((float)p[0], (float)p[1]);
}
static __device__ __forceinline__ float unpack1f(unsigned short u) {
    return (float)__builtin_bit_cast(_Float16, u);
}
static __device__ __forceinline__ unsigned short pack1f(float a) {
    return __builtin_bit_cast(unsigned short, (_Float16)a);
}

// ---------------- helpers ----------------
__global__ void k_zero_int(int* __restrict__ p, int n) {
    int i = blockIdx.x * 256 + threadIdx.x;
    if (i < n) p[i] = 0;
}

// count degree AND record each edge's rank within its dst node (atomic return).
__global__ void k_count_rank(const int* __restrict__ dst, int* __restrict__ deg,
                             int* __restrict__ rank) {
    int e = blockIdx.x * 256 + threadIdx.x;
    if (e < NE) rank[e] = atomicAdd(&deg[dst[e]], 1);
}

// ---------------- hierarchical exclusive scan ----------------
__global__ __launch_bounds__(256) void k_scan_blocksums(const int* __restrict__ deg,
                                                        int* __restrict__ blk) {
    __shared__ int s[256];
    int i = blockIdx.x * 256 + threadIdx.x;
    s[threadIdx.x] = (i < NN) ? deg[i] : 0;
    __syncthreads();
    for (int off = 128; off > 0; off >>= 1) {
        if (threadIdx.x < off) s[threadIdx.x] += s[threadIdx.x + off];
        __syncthreads();
    }
    if (threadIdx.x == 0) blk[blockIdx.x] = s[0];
}

__global__ __launch_bounds__(512) void k_scan_toplevel(int* __restrict__ blk) {
    __shared__ int s[512];
    int t = threadIdx.x;
    int v = (t < NB) ? blk[t] : 0;
    s[t] = v;
    for (int off = 1; off < 512; off <<= 1) {
        __syncthreads();
        int x = (t >= off) ? s[t - off] : 0;
        __syncthreads();
        s[t] += x;
    }
    __syncthreads();
    if (t < NB) blk[t] = s[t] - v;   // exclusive
}

// scan deg -> offsets in place, AND compute dinv from the pre-scan deg value.
__global__ __launch_bounds__(256) void k_scan_final(int* __restrict__ degoff,
                                                    const int* __restrict__ blk,
                                                    float* __restrict__ dinv) {
    __shared__ int s[256];
    int t = threadIdx.x;
    int i = blockIdx.x * 256 + t;
    int v = (i < NN) ? degoff[i] : 0;
    s[t] = v;
    for (int off = 1; off < 256; off <<= 1) {
        __syncthreads();
        int x = (t >= off) ? s[t - off] : 0;
        __syncthreads();
        s[t] += x;
    }
    __syncthreads();
    if (i < NN) {
        degoff[i] = s[t] - v + blk[blockIdx.x];
        dinv[i] = rsqrtf((float)v + 1.0f);
    }
    if (i == 0) degoff[NN] = NE;
}

// ---------------- mega: CSR fill (no atomics) + W-fragment prep + xs scale ----------------
// W-fragment order for mfma_f32_16x16x32_f16, operand A = W-tile:
//   Wf[(ct*KS + ks)*64 + lane][j] = (fp16) W[k*M + n]
//   with n = ct*16 + (lane&15), k = ks*32 + (lane>>4)*8 + j.
#define FILL_BLOCKS 6250          // NE / 256
#define PREP_BLOCKS 128           // 32768 / 256
#define SCALE_BLOCKS 3125         // NN*8 / 256
__global__ __launch_bounds__(256) void k_mega(
        const int* __restrict__ src, const int* __restrict__ dst,
        const int* __restrict__ rank, const int* __restrict__ off,
        int* __restrict__ csr,
        const float* __restrict__ W1, const float* __restrict__ W2,
        const float* __restrict__ W3, unsigned short* __restrict__ Wf1,
        unsigned short* __restrict__ Wf2, unsigned short* __restrict__ Wf3,
        const float* __restrict__ x, const float* __restrict__ dinv,
        unsigned short* __restrict__ xs) {
    int b = blockIdx.x;
    if (b < FILL_BLOCKS) {
        int e = b * 256 + threadIdx.x;
        int n = dst[e];
        csr[off[n] + rank[e]] = src[e];
    } else if (b < FILL_BLOCKS + PREP_BLOCKS) {
        int i = (b - FILL_BLOCKS) * 256 + threadIdx.x;   // 0..32767
        if (i < 8192) {            // Wf1: K=64 (KS=2), M=128 (CT=8)
            int j = i & 7, lane = (i >> 3) & 63, ksct = i >> 9;
            int ks = ksct & 1, ct = ksct >> 1;
            int n = ct * 16 + (lane & 15);
            int k = ks * 32 + (lane >> 4) * 8 + j;
            Wf1[i] = pack1f(W1[k * 128 + n]);
        } else if (i < 24576) {    // Wf2: K=128 (KS=4), M=128 (CT=8)
            int q = i - 8192;
            int j = q & 7, lane = (q >> 3) & 63, ksct = q >> 9;
            int ks = ksct & 3, ct = ksct >> 2;
            int n = ct * 16 + (lane & 15);
            int k = ks * 32 + (lane >> 4) * 8 + j;
            Wf2[q] = pack1f(W2[k * 128 + n]);
        } else {                   // Wf3: K=128 (KS=4), M=64 (CT=4)
            int q = i - 24576;
            int j = q & 7, lane = (q >> 3) & 63, ksct = q >> 9;
            int ks = ksct & 3, ct = ksct >> 2;
            int n = ct * 16 + (lane & 15);
            int k = ks * 32 + (lane >> 4) * 8 + j;
            Wf3[q] = pack1f(W3[k * 64 + n]);
        }
    } else {
        int i = (b - FILL_BLOCKS - PREP_BLOCKS) * 256 + threadIdx.x;  // 0..799999
        int row = i >> 3, c8 = i & 7;                     // 8 cols per thread
        float d = dinv[row];
        const float4* xp = (const float4*)(x + (size_t)row * 64 + c8 * 8);
        float4 f0 = xp[0], f1 = xp[1];
        uint4 o;
        o.x = pack2f(f0.x * d, f0.y * d);
        o.y = pack2f(f0.z * d, f0.w * d);
        o.z = pack2f(f1.x * d, f1.y * d);
        o.w = pack2f(f1.z * d, f1.w * d);
        *(uint4*)(xs + (size_t)row * 64 + c8 * 8) = o;
    }
}

// ---------------- 64-wide fp16 gather -> fp16 agg ----------------
__global__ __launch_bounds__(256) void k_gather64_f16(
        const unsigned short* __restrict__ xs, const int* __restrict__ off,
        const int* __restrict__ csr, const float* __restrict__ dinv,
        unsigned short* __restrict__ agg) {
    int n = blockIdx.x * 4 + (threadIdx.x >> 6);
    if (n >= NN) return;
    int lane = threadIdx.x & 63;

    int beg = off[n], end = off[n + 1];
    float a0 = 0.f, a1 = 0.f, a2 = 0.f, a3 = 0.f;
    int e = beg;
    for (; e + 4 <= end; e += 4) {
        int s0 = csr[e], s1 = csr[e + 1], s2 = csr[e + 2], s3 = csr[e + 3];
        a0 += unpack1f(xs[(size_t)s0 * 64 + lane]);
        a1 += unpack1f(xs[(size_t)s1 * 64 + lane]);
        a2 += unpack1f(xs[(size_t)s2 * 64 + lane]);
        a3 += unpack1f(xs[(size_t)s3 * 64 + lane]);
    }
    for (; e < end; ++e) a0 += unpack1f(xs[(size_t)csr[e] * 64 + lane]);

    float v = (a0 + a1 + a2 + a3 + unpack1f(xs[(size_t)n * 64 + lane])) * dinv[n];
    agg[(size_t)n * 64 + lane] = pack1f(v);
}

// ---------------- 128-wide gather, fp16 in -> fp16 agg ----------------
__global__ __launch_bounds__(256) void k_gather128_f16(
        const unsigned short* __restrict__ h1, const int* __restrict__ off,
        const int* __restrict__ csr, const float* __restrict__ dinv,
        unsigned short* __restrict__ agg) {
    int n = blockIdx.x * 4 + (threadIdx.x >> 6);
    if (n >= NN) return;
    int lane = threadIdx.x & 63;
    const unsigned int* h = (const unsigned int*)h1;   // half2 per lane, row stride 64

    int beg = off[n], end = off[n + 1];
    float ax = 0.f, ay = 0.f, bx = 0.f, by = 0.f;
    float cx = 0.f, cy = 0.f, dx = 0.f, dy = 0.f;
    int e = beg;
    for (; e + 4 <= end; e += 4) {
        int s0 = csr[e], s1 = csr[e + 1], s2 = csr[e + 2], s3 = csr[e + 3];
        float2 u0 = unpack2f(h[(size_t)s0 * 64 + lane]);
        float2 u1 = unpack2f(h[(size_t)s1 * 64 + lane]);
        float2 u2 = unpack2f(h[(size_t)s2 * 64 + lane]);
        float2 u3 = unpack2f(h[(size_t)s3 * 64 + lane]);
        ax += u0.x; ay += u0.y;
        bx += u1.x; by += u1.y;
        cx += u2.x; cy += u2.y;
        dx += u3.x; dy += u3.y;
    }
    for (; e < end; ++e) {
        float2 u0 = unpack2f(h[(size_t)csr[e] * 64 + lane]);
        ax += u0.x; ay += u0.y;
    }
    float2 self = unpack2f(h[(size_t)n * 64 + lane]);
    float dn = dinv[n];
    ((unsigned int*)agg)[(size_t)n * 64 + lane] =
        pack2f((ax + bx + cx + dx + self.x) * dn,
               (ay + by + cy + dy + self.y) * dn);
}

// ---------------- MFMA GEMM: out = epilogue(agg @ W) ----------------
// 4 waves/block, wave = 16-row strip x all M cols. B-frags (agg rows) direct
// from global (16B/lane); A-frags (W) staged linearly in LDS in fragment order.
// mfma(Wtile, aggrows): lane l, reg j -> out[row0+(l&15)][ct*16+(l>>4)*4+j].
// EPI 1: BN+ReLU+*dinv. EPI 2: BN+ReLU. EPI 3: *dinv. All write fp16.
template <int K, int M, int EPI>
__global__ __launch_bounds__(256) void k_gemm_mfma(
        const unsigned short* __restrict__ A, const unsigned short* __restrict__ Wf,
        const float* __restrict__ dinv, const float* __restrict__ bias,
        const float* __restrict__ g, const float* __restrict__ be,
        const float* __restrict__ mn, const float* __restrict__ vr,
        unsigned short* __restrict__ outp) {
    constexpr int KS = K / 32;
    constexpr int CT = M / 16;
    __shared__ __align__(16) unsigned short sWf[CT * KS * 64 * 8];
    __shared__ float sSc[M], sSh[M];

    int tid = threadIdx.x;
    {
        const uint4* s = (const uint4*)Wf;
        uint4* d = (uint4*)sWf;
        constexpr int W4 = CT * KS * 64;     // 16B chunks
#pragma unroll
        for (int i = tid; i < W4; i += 256) d[i] = s[i];
    }
    if constexpr (EPI == 1 || EPI == 2) {
        for (int c = tid; c < M; c += 256) {
            float s = g[c] * rsqrtf(vr[c] + BN_EPS);
            sSc[c] = s;
            sSh[c] = (bias[c] - mn[c]) * s + be[c];
        }
    }
    __syncthreads();

    int wave = tid >> 6, lane = tid & 63;
    int row0 = blockIdx.x * 64 + wave * 16;
    if (row0 >= NN) return;
    int r  = row0 + (lane & 15);
    int kq = lane >> 4;

    // B-fragments: agg row r, k-chunks
    f16x8 bf[KS];
#pragma unroll
    for (int ks = 0; ks < KS; ++ks)
        bf[ks] = *(const f16x8*)(A + (size_t)r * K + ks * 32 + kq * 8);

    float dr = dinv[r];
    const f16x8* wfp = (const f16x8*)sWf;
#pragma unroll
    for (int ct = 0; ct < CT; ++ct) {
        f32x4 acc = {0.f, 0.f, 0.f, 0.f};
#pragma unroll
        for (int ks = 0; ks < KS; ++ks)
            acc = __builtin_amdgcn_mfma_f32_16x16x32_f16(
                wfp[(ct * KS + ks) * 64 + lane], bf[ks], acc, 0, 0, 0);

        int c4 = ct * 16 + kq * 4;
        unsigned short* op = outp + (size_t)r * M + c4;
        if constexpr (EPI == 1 || EPI == 2) {
            float v0 = fmaxf(acc[0] * sSc[c4 + 0] + sSh[c4 + 0], 0.f);
            float v1 = fmaxf(acc[1] * sSc[c4 + 1] + sSh[c4 + 1], 0.f);
            float v2 = fmaxf(acc[2] * sSc[c4 + 2] + sSh[c4 + 2], 0.f);
            float v3 = fmaxf(acc[3] * sSc[c4 + 3] + sSh[c4 + 3], 0.f);
            if constexpr (EPI == 1) { v0 *= dr; v1 *= dr; v2 *= dr; v3 *= dr; }
            uint2 o; o.x = pack2f(v0, v1); o.y = pack2f(v2, v3);
            *(uint2*)op = o;
        } else {
            uint2 o;
            o.x = pack2f(acc[0] * dr, acc[1] * dr);
            o.y = pack2f(acc[2] * dr, acc[3] * dr);
            *(uint2*)op = o;
        }
    }
}

// ---------------- final: gather fp16 + b3 + ReLU + (·Wo + bo) ----------------
__global__ __launch_bounds__(256) void k_gather_final_f16(
        const unsigned short* __restrict__ hs, const int* __restrict__ off,
        const int* __restrict__ csr, const float* __restrict__ dinv,
        const float* __restrict__ b, const float* __restrict__ Wo,
        const float* __restrict__ bo, float* __restrict__ out) {
    int n = blockIdx.x * 4 + (threadIdx.x >> 6);
    if (n >= NN) return;
    int lane = threadIdx.x & 63;

    int beg = off[n], end = off[n + 1];
    float a0 = 0.f, a1 = 0.f, a2 = 0.f, a3 = 0.f;
    int e = beg;
    for (; e + 4 <= end; e += 4) {
        int s0 = csr[e], s1 = csr[e + 1], s2 = csr[e + 2], s3 = csr[e + 3];
        a0 += unpack1f(hs[(size_t)s0 * 64 + lane]);
        a1 += unpack1f(hs[(size_t)s1 * 64 + lane]);
        a2 += unpack1f(hs[(size_t)s2 * 64 + lane]);
        a3 += unpack1f(hs[(size_t)s3 * 64 + lane]);
    }
    for (; e < end; ++e) a0 += unpack1f(hs[(size_t)csr[e] * 64 + lane]);

    float val = (a0 + a1 + a2 + a3 + unpack1f(hs[(size_t)n * 64 + lane])) * dinv[n]
                + b[lane];
    val = fmaxf(val, 0.f) * Wo[lane];
#pragma unroll
    for (int o = 32; o > 0; o >>= 1) val += __shfl_down(val, o, 64);
    if (lane == 0) out[n] = val + bo[0];
}

extern "C" void kernel_launch(void* const* d_in, const int* in_sizes, int n_in,
                              void* d_out, int out_size, void* d_ws, size_t ws_size,
                              hipStream_t stream) {
    const float* x   = (const float*)d_in[0];
    const int*   ei  = (const int*)d_in[1];
    const int*   src = ei;
    const int*   dst = ei + NE;
    const float* W1  = (const float*)d_in[2];
    const float* b1  = (const float*)d_in[3];
    const float* g1  = (const float*)d_in[4];
    const float* be1 = (const float*)d_in[5];
    const float* m1  = (const float*)d_in[6];
    const float* v1  = (const float*)d_in[7];
    const float* W2  = (const float*)d_in[8];
    const float* b2  = (const float*)d_in[9];
    const float* g2  = (const float*)d_in[10];
    const float* be2 = (const float*)d_in[11];
    const float* m2  = (const float*)d_in[12];
    const float* v2  = (const float*)d_in[13];
    const float* W3  = (const float*)d_in[14];
    const float* b3  = (const float*)d_in[15];
    const float* Wo  = (const float*)d_in[16];
    const float* bo  = (const float*)d_in[17];
    float* out = (float*)d_out;

    char* ws = (char*)d_ws;
    float* dinv   = (float*)(ws + 0);              // 400,000 B
    int*   degoff = (int*)(ws + 400032);           // (N+1) ints -> 800,036
    int*   blk    = (int*)(ws + 800064);           // NB ints -> 801,628
    unsigned short* Wf1 = (unsigned short*)(ws + 801664);   // 16,384 B
    unsigned short* Wf2 = (unsigned short*)(ws + 818048);   // 32,768 B
    unsigned short* Wf3 = (unsigned short*)(ws + 850816);   // 16,384 B -> 867,200
    int*   csr    = (int*)(ws + 867200);           // 6,400,000 B -> 7,267,200
    char*  S1     = ws + 7267200;                  // 51.2 MB: xs(f16)->h1ps(f16)->h2p(f16)
    char*  S2     = ws + 58467200;                 // 51.2 MB: rank->aggX(f16)->aggH1(f16)->hs3(f16)

    unsigned short* xs    = (unsigned short*)S1;
    unsigned short* h1ps  = (unsigned short*)S1;
    unsigned short* h2p   = (unsigned short*)S1;
    int*            rank  = (int*)S2;
    unsigned short* aggX  = (unsigned short*)S2;
    unsigned short* aggH1 = (unsigned short*)S2;
    unsigned short* hs3   = (unsigned short*)S2;

    int gN = (NN + 255) / 256;
    int gE = (NE + 255) / 256;
    int gW = (NN + 3) / 4;
    int gG = (NN + 63) / 64;     // MFMA GEMM: 64 rows/block

    // ---- CSR build (rank trick) + dinv ----
    k_zero_int<<<gN, 256, 0, stream>>>(degoff, NN);
    k_count_rank<<<gE, 256, 0, stream>>>(dst, degoff, rank);
    k_scan_blocksums<<<NB, 256, 0, stream>>>(degoff, blk);
    k_scan_toplevel<<<1, 512, 0, stream>>>(blk);
    k_scan_final<<<NB, 256, 0, stream>>>(degoff, blk, dinv);

    // ---- mega: CSR fill + W-fragment fp16 prep + xs = x*dinv (fp16) ----
    k_mega<<<FILL_BLOCKS + PREP_BLOCKS + SCALE_BLOCKS, 256, 0, stream>>>(
        src, dst, rank, degoff, csr, W1, W2, W3, Wf1, Wf2, Wf3, x, dinv, xs);

    // ---- layer 1: gather(xs) -> aggX(f16) ; MFMA GEMM1 + BN + ReLU + *dinv -> h1ps(f16) ----
    k_gather64_f16<<<gW, 256, 0, stream>>>(xs, degoff, csr, dinv, aggX);
    k_gemm_mfma<64, 128, 1><<<gG, 256, 0, stream>>>(
        aggX, Wf1, dinv, b1, g1, be1, m1, v1, h1ps);

    // ---- layer 2: gather(h1ps) -> aggH1(f16) ; MFMA GEMM2 + BN + ReLU -> h2p(f16) ----
    k_gather128_f16<<<gW, 256, 0, stream>>>(h1ps, degoff, csr, dinv, aggH1);
    k_gemm_mfma<128, 128, 2><<<gG, 256, 0, stream>>>(
        aggH1, Wf2, dinv, b2, g2, be2, m2, v2, h2p);

    // ---- layer 3: MFMA GEMM3 (*dinv) -> hs3(f16) ; final gather + dot ----
    k_gemm_mfma<128, 64, 3><<<gG, 256, 0, stream>>>(
        h2p, Wf3, dinv, nullptr, nullptr, nullptr, nullptr, nullptr, hs3);
    k_gather_final_f16<<<gW, 256, 0, stream>>>(hs3, degoff, csr, dinv,
                                               b3, Wo, bo, out);
}

// Round 10
// 351.227 us; speedup vs baseline: 2.5308x; 1.0363x over previous
//
#include <hip/hip_runtime.h>

#define NN 100000
#define NE 1600000
#define NB 391          // ceil(NN/256) blocks for scan
#define BN_EPS 1e-5f

typedef _Float16 h2 __attribute__((ext_vector_type(2)));
typedef _Float16 f16x8 __attribute__((ext_vector_type(8)));
typedef float f32x4 __attribute__((ext_vector_type(4)));

static __device__ __forceinline__ unsigned int pack2f(float a, float b) {
    h2 p; p[0] = (_Float16)a; p[1] = (_Float16)b;
    return __builtin_bit_cast(unsigned int, p);
}
static __device__ __forceinline__ float2 unpack2f(unsigned int u) {
    h2 p = __builtin_bit_cast(h2, u);
    return make_float2((float)p[0], (float)p[1]);
}
static __device__ __forceinline__ float unpack1f(unsigned short u) {
    return (float)__builtin_bit_cast(_Float16, u);
}
static __device__ __forceinline__ unsigned short pack1f(float a) {
    return __builtin_bit_cast(unsigned short, (_Float16)a);
}

#define FILL_BLOCKS 6250          // NE / 256
#define PREP_BLOCKS 128           // 32768 / 256
#define SCALE_BLOCKS 3125         // NN*8 / 256

// ---------------- helpers ----------------
__global__ void k_zero_int(int* __restrict__ p, int n) {
    int i = blockIdx.x * 256 + threadIdx.x;
    if (i < n) p[i] = 0;
}

// count degree + edge rank (atomic return); W-fragment prep rides along.
__global__ __launch_bounds__(256) void k_count_rank_prep(
        const int* __restrict__ dst, int* __restrict__ deg, int* __restrict__ rank,
        const float* __restrict__ W1, const float* __restrict__ W2,
        const float* __restrict__ W3, unsigned short* __restrict__ Wf1,
        unsigned short* __restrict__ Wf2, unsigned short* __restrict__ Wf3) {
    int b = blockIdx.x;
    if (b < FILL_BLOCKS) {
        int e = b * 256 + threadIdx.x;
        rank[e] = atomicAdd(&deg[dst[e]], 1);
    } else {
        int i = (b - FILL_BLOCKS) * 256 + threadIdx.x;   // 0..32767
        if (i < 8192) {            // Wf1: K=64 (KS=2), M=128 (CT=8)
            int j = i & 7, lane = (i >> 3) & 63, ksct = i >> 9;
            int ks = ksct & 1, ct = ksct >> 1;
            int n = ct * 16 + (lane & 15);
            int k = ks * 32 + (lane >> 4) * 8 + j;
            Wf1[i] = pack1f(W1[k * 128 + n]);
        } else if (i < 24576) {    // Wf2: K=128 (KS=4), M=128 (CT=8)
            int q = i - 8192;
            int j = q & 7, lane = (q >> 3) & 63, ksct = q >> 9;
            int ks = ksct & 3, ct = ksct >> 2;
            int n = ct * 16 + (lane & 15);
            int k = ks * 32 + (lane >> 4) * 8 + j;
            Wf2[q] = pack1f(W2[k * 128 + n]);
        } else {                   // Wf3: K=128 (KS=4), M=64 (CT=4)
            int q = i - 24576;
            int j = q & 7, lane = (q >> 3) & 63, ksct = q >> 9;
            int ks = ksct & 3, ct = ksct >> 2;
            int n = ct * 16 + (lane & 15);
            int k = ks * 32 + (lane >> 4) * 8 + j;
            Wf3[q] = pack1f(W3[k * 64 + n]);
        }
    }
}

// ---------------- hierarchical exclusive scan ----------------
__global__ __launch_bounds__(256) void k_scan_blocksums(const int* __restrict__ deg,
                                                        int* __restrict__ blk) {
    __shared__ int s[256];
    int i = blockIdx.x * 256 + threadIdx.x;
    s[threadIdx.x] = (i < NN) ? deg[i] : 0;
    __syncthreads();
    for (int off = 128; off > 0; off >>= 1) {
        if (threadIdx.x < off) s[threadIdx.x] += s[threadIdx.x + off];
        __syncthreads();
    }
    if (threadIdx.x == 0) blk[blockIdx.x] = s[0];
}

__global__ __launch_bounds__(512) void k_scan_toplevel(int* __restrict__ blk) {
    __shared__ int s[512];
    int t = threadIdx.x;
    int v = (t < NB) ? blk[t] : 0;
    s[t] = v;
    for (int off = 1; off < 512; off <<= 1) {
        __syncthreads();
        int x = (t >= off) ? s[t - off] : 0;
        __syncthreads();
        s[t] += x;
    }
    __syncthreads();
    if (t < NB) blk[t] = s[t] - v;   // exclusive
}

// scan deg -> offsets in place, AND compute dinv from the pre-scan deg value.
__global__ __launch_bounds__(256) void k_scan_final(int* __restrict__ degoff,
                                                    const int* __restrict__ blk,
                                                    float* __restrict__ dinv) {
    __shared__ int s[256];
    int t = threadIdx.x;
    int i = blockIdx.x * 256 + t;
    int v = (i < NN) ? degoff[i] : 0;
    s[t] = v;
    for (int off = 1; off < 256; off <<= 1) {
        __syncthreads();
        int x = (t >= off) ? s[t - off] : 0;
        __syncthreads();
        s[t] += x;
    }
    __syncthreads();
    if (i < NN) {
        degoff[i] = s[t] - v + blk[blockIdx.x];
        dinv[i] = rsqrtf((float)v + 1.0f);
    }
    if (i == 0) degoff[NN] = NE;
}

// ---------------- fill (atomic-free, NT stores) + xs scale ----------------
__global__ __launch_bounds__(256) void k_fill_scale(
        const int* __restrict__ src, const int* __restrict__ dst,
        const int* __restrict__ rank, const int* __restrict__ off,
        int* __restrict__ csr,
        const float* __restrict__ x, const float* __restrict__ dinv,
        unsigned short* __restrict__ xs) {
    int b = blockIdx.x;
    if (b < FILL_BLOCKS) {
        int e = b * 256 + threadIdx.x;
        int n = dst[e];
        __builtin_nontemporal_store(src[e], &csr[off[n] + rank[e]]);
    } else {
        int i = (b - FILL_BLOCKS) * 256 + threadIdx.x;  // 0..799999
        int row = i >> 3, c8 = i & 7;                   // 8 cols per thread
        float d = dinv[row];
        const float4* xp = (const float4*)(x + (size_t)row * 64 + c8 * 8);
        float4 f0 = xp[0], f1 = xp[1];
        uint4 o;
        o.x = pack2f(f0.x * d, f0.y * d);
        o.y = pack2f(f0.z * d, f0.w * d);
        o.z = pack2f(f1.x * d, f1.y * d);
        o.w = pack2f(f1.z * d, f1.w * d);
        *(uint4*)(xs + (size_t)row * 64 + c8 * 8) = o;
    }
}

// ---------------- 64-wide fp16 gather -> fp16 agg (unroll 8) ----------------
__global__ __launch_bounds__(256) void k_gather64_f16(
        const unsigned short* __restrict__ xs, const int* __restrict__ off,
        const int* __restrict__ csr, const float* __restrict__ dinv,
        unsigned short* __restrict__ agg) {
    int n = blockIdx.x * 4 + (threadIdx.x >> 6);
    if (n >= NN) return;
    int lane = threadIdx.x & 63;

    int beg = off[n], end = off[n + 1];
    float a0 = 0.f, a1 = 0.f, a2 = 0.f, a3 = 0.f;
    int e = beg;
    for (; e + 8 <= end; e += 8) {
        int s0 = csr[e],     s1 = csr[e + 1], s2 = csr[e + 2], s3 = csr[e + 3];
        int s4 = csr[e + 4], s5 = csr[e + 5], s6 = csr[e + 6], s7 = csr[e + 7];
        unsigned short u0 = xs[(size_t)s0 * 64 + lane];
        unsigned short u1 = xs[(size_t)s1 * 64 + lane];
        unsigned short u2 = xs[(size_t)s2 * 64 + lane];
        unsigned short u3 = xs[(size_t)s3 * 64 + lane];
        unsigned short u4 = xs[(size_t)s4 * 64 + lane];
        unsigned short u5 = xs[(size_t)s5 * 64 + lane];
        unsigned short u6 = xs[(size_t)s6 * 64 + lane];
        unsigned short u7 = xs[(size_t)s7 * 64 + lane];
        a0 += unpack1f(u0); a1 += unpack1f(u1);
        a2 += unpack1f(u2); a3 += unpack1f(u3);
        a0 += unpack1f(u4); a1 += unpack1f(u5);
        a2 += unpack1f(u6); a3 += unpack1f(u7);
    }
    for (; e + 2 <= end; e += 2) {
        a0 += unpack1f(xs[(size_t)csr[e] * 64 + lane]);
        a1 += unpack1f(xs[(size_t)csr[e + 1] * 64 + lane]);
    }
    if (e < end) a0 += unpack1f(xs[(size_t)csr[e] * 64 + lane]);

    float v = (a0 + a1 + a2 + a3 + unpack1f(xs[(size_t)n * 64 + lane])) * dinv[n];
    agg[(size_t)n * 64 + lane] = pack1f(v);
}

// ---------------- 128-wide gather, fp16 in -> fp16 agg (unroll 8) ----------------
__global__ __launch_bounds__(256) void k_gather128_f16(
        const unsigned short* __restrict__ h1, const int* __restrict__ off,
        const int* __restrict__ csr, const float* __restrict__ dinv,
        unsigned short* __restrict__ agg) {
    int n = blockIdx.x * 4 + (threadIdx.x >> 6);
    if (n >= NN) return;
    int lane = threadIdx.x & 63;
    const unsigned int* h = (const unsigned int*)h1;   // half2 per lane, row stride 64

    int beg = off[n], end = off[n + 1];
    float ax = 0.f, ay = 0.f, bx = 0.f, by = 0.f;
    float cx = 0.f, cy = 0.f, dx = 0.f, dy = 0.f;
    int e = beg;
    for (; e + 8 <= end; e += 8) {
        int s0 = csr[e],     s1 = csr[e + 1], s2 = csr[e + 2], s3 = csr[e + 3];
        int s4 = csr[e + 4], s5 = csr[e + 5], s6 = csr[e + 6], s7 = csr[e + 7];
        unsigned int u0 = h[(size_t)s0 * 64 + lane];
        unsigned int u1 = h[(size_t)s1 * 64 + lane];
        unsigned int u2 = h[(size_t)s2 * 64 + lane];
        unsigned int u3 = h[(size_t)s3 * 64 + lane];
        unsigned int u4 = h[(size_t)s4 * 64 + lane];
        unsigned int u5 = h[(size_t)s5 * 64 + lane];
        unsigned int u6 = h[(size_t)s6 * 64 + lane];
        unsigned int u7 = h[(size_t)s7 * 64 + lane];
        float2 v0 = unpack2f(u0), v1 = unpack2f(u1), v2 = unpack2f(u2), v3 = unpack2f(u3);
        float2 v4 = unpack2f(u4), v5 = unpack2f(u5), v6 = unpack2f(u6), v7 = unpack2f(u7);
        ax += v0.x; ay += v0.y;  bx += v1.x; by += v1.y;
        cx += v2.x; cy += v2.y;  dx += v3.x; dy += v3.y;
        ax += v4.x; ay += v4.y;  bx += v5.x; by += v5.y;
        cx += v6.x; cy += v6.y;  dx += v7.x; dy += v7.y;
    }
    for (; e + 2 <= end; e += 2) {
        float2 v0 = unpack2f(h[(size_t)csr[e] * 64 + lane]);
        float2 v1 = unpack2f(h[(size_t)csr[e + 1] * 64 + lane]);
        ax += v0.x; ay += v0.y;  bx += v1.x; by += v1.y;
    }
    if (e < end) {
        float2 v0 = unpack2f(h[(size_t)csr[e] * 64 + lane]);
        ax += v0.x; ay += v0.y;
    }
    float2 self = unpack2f(h[(size_t)n * 64 + lane]);
    float dn = dinv[n];
    ((unsigned int*)agg)[(size_t)n * 64 + lane] =
        pack2f((ax + bx + cx + dx + self.x) * dn,
               (ay + by + cy + dy + self.y) * dn);
}

// ---------------- MFMA GEMM: out = epilogue(agg @ W) ----------------
// 4 waves/block, wave = 16-row strip x all M cols. B-frags (agg rows) direct
// from global (16B/lane); A-frags (W) staged linearly in LDS in fragment order.
// mfma(Wtile, aggrows): lane l, reg j -> out[row0+(l&15)][ct*16+(l>>4)*4+j].
// EPI 1: BN+ReLU+*dinv. EPI 2: BN+ReLU. EPI 3: *dinv. All write fp16.
template <int K, int M, int EPI>
__global__ __launch_bounds__(256) void k_gemm_mfma(
        const unsigned short* __restrict__ A, const unsigned short* __restrict__ Wf,
        const float* __restrict__ dinv, const float* __restrict__ bias,
        const float* __restrict__ g, const float* __restrict__ be,
        const float* __restrict__ mn, const float* __restrict__ vr,
        unsigned short* __restrict__ outp) {
    constexpr int KS = K / 32;
    constexpr int CT = M / 16;
    __shared__ __align__(16) unsigned short sWf[CT * KS * 64 * 8];
    __shared__ float sSc[M], sSh[M];

    int tid = threadIdx.x;
    {
        const uint4* s = (const uint4*)Wf;
        uint4* d = (uint4*)sWf;
        constexpr int W4 = CT * KS * 64;     // 16B chunks
#pragma unroll
        for (int i = tid; i < W4; i += 256) d[i] = s[i];
    }
    if constexpr (EPI == 1 || EPI == 2) {
        for (int c = tid; c < M; c += 256) {
            float s = g[c] * rsqrtf(vr[c] + BN_EPS);
            sSc[c] = s;
            sSh[c] = (bias[c] - mn[c]) * s + be[c];
        }
    }
    __syncthreads();

    int wave = tid >> 6, lane = tid & 63;
    int row0 = blockIdx.x * 64 + wave * 16;
    if (row0 >= NN) return;
    int r  = row0 + (lane & 15);
    int kq = lane >> 4;

    // B-fragments: agg row r, k-chunks
    f16x8 bf[KS];
#pragma unroll
    for (int ks = 0; ks < KS; ++ks)
        bf[ks] = *(const f16x8*)(A + (size_t)r * K + ks * 32 + kq * 8);

    float dr = dinv[r];
    const f16x8* wfp = (const f16x8*)sWf;
#pragma unroll
    for (int ct = 0; ct < CT; ++ct) {
        f32x4 acc = {0.f, 0.f, 0.f, 0.f};
#pragma unroll
        for (int ks = 0; ks < KS; ++ks)
            acc = __builtin_amdgcn_mfma_f32_16x16x32_f16(
                wfp[(ct * KS + ks) * 64 + lane], bf[ks], acc, 0, 0, 0);

        int c4 = ct * 16 + kq * 4;
        unsigned short* op = outp + (size_t)r * M + c4;
        if constexpr (EPI == 1 || EPI == 2) {
            float v0 = fmaxf(acc[0] * sSc[c4 + 0] + sSh[c4 + 0], 0.f);
            float v1 = fmaxf(acc[1] * sSc[c4 + 1] + sSh[c4 + 1], 0.f);
            float v2 = fmaxf(acc[2] * sSc[c4 + 2] + sSh[c4 + 2], 0.f);
            float v3 = fmaxf(acc[3] * sSc[c4 + 3] + sSh[c4 + 3], 0.f);
            if constexpr (EPI == 1) { v0 *= dr; v1 *= dr; v2 *= dr; v3 *= dr; }
            uint2 o; o.x = pack2f(v0, v1); o.y = pack2f(v2, v3);
            *(uint2*)op = o;
        } else {
            uint2 o;
            o.x = pack2f(acc[0] * dr, acc[1] * dr);
            o.y = pack2f(acc[2] * dr, acc[3] * dr);
            *(uint2*)op = o;
        }
    }
}

// ---------------- final: gather fp16 + b3 + ReLU + (·Wo + bo) (unroll 8) ----------------
__global__ __launch_bounds__(256) void k_gather_final_f16(
        const unsigned short* __restrict__ hs, const int* __restrict__ off,
        const int* __restrict__ csr, const float* __restrict__ dinv,
        const float* __restrict__ b, const float* __restrict__ Wo,
        const float* __restrict__ bo, float* __restrict__ out) {
    int n = blockIdx.x * 4 + (threadIdx.x >> 6);
    if (n >= NN) return;
    int lane = threadIdx.x & 63;

    int beg = off[n], end = off[n + 1];
    float a0 = 0.f, a1 = 0.f, a2 = 0.f, a3 = 0.f;
    int e = beg;
    for (; e + 8 <= end; e += 8) {
        int s0 = csr[e],     s1 = csr[e + 1], s2 = csr[e + 2], s3 = csr[e + 3];
        int s4 = csr[e + 4], s5 = csr[e + 5], s6 = csr[e + 6], s7 = csr[e + 7];
        a0 += unpack1f(hs[(size_t)s0 * 64 + lane]);
        a1 += unpack1f(hs[(size_t)s1 * 64 + lane]);
        a2 += unpack1f(hs[(size_t)s2 * 64 + lane]);
        a3 += unpack1f(hs[(size_t)s3 * 64 + lane]);
        a0 += unpack1f(hs[(size_t)s4 * 64 + lane]);
        a1 += unpack1f(hs[(size_t)s5 * 64 + lane]);
        a2 += unpack1f(hs[(size_t)s6 * 64 + lane]);
        a3 += unpack1f(hs[(size_t)s7 * 64 + lane]);
    }
    for (; e + 2 <= end; e += 2) {
        a0 += unpack1f(hs[(size_t)csr[e] * 64 + lane]);
        a1 += unpack1f(hs[(size_t)csr[e + 1] * 64 + lane]);
    }
    if (e < end) a0 += unpack1f(hs[(size_t)csr[e] * 64 + lane]);

    float val = (a0 + a1 + a2 + a3 + unpack1f(hs[(size_t)n * 64 + lane])) * dinv[n]
                + b[lane];
    val = fmaxf(val, 0.f) * Wo[lane];
#pragma unroll
    for (int o = 32; o > 0; o >>= 1) val += __shfl_down(val, o, 64);
    if (lane == 0) out[n] = val + bo[0];
}

extern "C" void kernel_launch(void* const* d_in, const int* in_sizes, int n_in,
                              void* d_out, int out_size, void* d_ws, size_t ws_size,
                              hipStream_t stream) {
    const float* x   = (const float*)d_in[0];
    const int*   ei  = (const int*)d_in[1];
    const int*   src = ei;
    const int*   dst = ei + NE;
    const float* W1  = (const float*)d_in[2];
    const float* b1  = (const float*)d_in[3];
    const float* g1  = (const float*)d_in[4];
    const float* be1 = (const float*)d_in[5];
    const float* m1  = (const float*)d_in[6];
    const float* v1  = (const float*)d_in[7];
    const float* W2  = (const float*)d_in[8];
    const float* b2  = (const float*)d_in[9];
    const float* g2  = (const float*)d_in[10];
    const float* be2 = (const float*)d_in[11];
    const float* m2  = (const float*)d_in[12];
    const float* v2  = (const float*)d_in[13];
    const float* W3  = (const float*)d_in[14];
    const float* b3  = (const float*)d_in[15];
    const float* Wo  = (const float*)d_in[16];
    const float* bo  = (const float*)d_in[17];
    float* out = (float*)d_out;

    char* ws = (char*)d_ws;
    float* dinv   = (float*)(ws + 0);              // 400,000 B
    int*   degoff = (int*)(ws + 400032);           // (N+1) ints -> 800,036
    int*   blk    = (int*)(ws + 800064);           // NB ints -> 801,628
    unsigned short* Wf1 = (unsigned short*)(ws + 801664);   // 16,384 B
    unsigned short* Wf2 = (unsigned short*)(ws + 818048);   // 32,768 B
    unsigned short* Wf3 = (unsigned short*)(ws + 850816);   // 16,384 B -> 867,200
    int*   csr    = (int*)(ws + 867200);           // 6,400,000 B -> 7,267,200
    char*  S1     = ws + 7267200;                  // 51.2 MB: xs(f16)->h1ps(f16)->h2p(f16)
    char*  S2     = ws + 58467200;                 // 51.2 MB: rank->aggX(f16)->aggH1(f16)->hs3(f16)

    unsigned short* xs    = (unsigned short*)S1;
    unsigned short* h1ps  = (unsigned short*)S1;
    unsigned short* h2p   = (unsigned short*)S1;
    int*            rank  = (int*)S2;
    unsigned short* aggX  = (unsigned short*)S2;
    unsigned short* aggH1 = (unsigned short*)S2;
    unsigned short* hs3   = (unsigned short*)S2;

    int gN = (NN + 255) / 256;
    int gW = (NN + 3) / 4;
    int gG = (NN + 63) / 64;     // MFMA GEMM: 64 rows/block

    // ---- CSR build (rank trick) + dinv; W-prep overlapped with count ----
    k_zero_int<<<gN, 256, 0, stream>>>(degoff, NN);
    k_count_rank_prep<<<FILL_BLOCKS + PREP_BLOCKS, 256, 0, stream>>>(
        dst, degoff, rank, W1, W2, W3, Wf1, Wf2, Wf3);
    k_scan_blocksums<<<NB, 256, 0, stream>>>(degoff, blk);
    k_scan_toplevel<<<1, 512, 0, stream>>>(blk);
    k_scan_final<<<NB, 256, 0, stream>>>(degoff, blk, dinv);

    // ---- fill (NT stores, atomic-free) + xs = x*dinv (fp16) ----
    k_fill_scale<<<FILL_BLOCKS + SCALE_BLOCKS, 256, 0, stream>>>(
        src, dst, rank, degoff, csr, x, dinv, xs);

    // ---- layer 1: gather(xs) -> aggX(f16) ; MFMA GEMM1 + BN + ReLU + *dinv -> h1ps(f16) ----
    k_gather64_f16<<<gW, 256, 0, stream>>>(xs, degoff, csr, dinv, aggX);
    k_gemm_mfma<64, 128, 1><<<gG, 256, 0, stream>>>(
        aggX, Wf1, dinv, b1, g1, be1, m1, v1, h1ps);

    // ---- layer 2: gather(h1ps) -> aggH1(f16) ; MFMA GEMM2 + BN + ReLU -> h2p(f16) ----
    k_gather128_f16<<<gW, 256, 0, stream>>>(h1ps, degoff, csr, dinv, aggH1);
    k_gemm_mfma<128, 128, 2><<<gG, 256, 0, stream>>>(
        aggH1, Wf2, dinv, b2, g2, be2, m2, v2, h2p);

    // ---- layer 3: MFMA GEMM3 (*dinv) -> hs3(f16) ; final gather + dot ----
    k_gemm_mfma<128, 64, 3><<<gG, 256, 0, stream>>>(
        h2p, Wf3, dinv, nullptr, nullptr, nullptr, nullptr, nullptr, hs3);
    k_gather_final_f16<<<gW, 256, 0, stream>>>(hs3, degoff, csr, dinv,
                                               b3, Wo, bo, out);
}